// Round 3
// baseline (628.907 us; speedup 1.0000x reference)
//
#include <hip/hip_runtime.h>
#include <math.h>

#define LL 1024
#define DD 512
#define NB 16

typedef __attribute__((ext_vector_type(8))) short bf16x8;
typedef __attribute__((ext_vector_type(4))) float f32x4;
typedef unsigned short u16;
typedef unsigned int u32;
typedef const __attribute__((address_space(1))) void* gptr_t;
typedef __attribute__((address_space(3))) void* sptr_t;

static const long NLD = (long)NB * LL * DD;  // 8,388,608
static const long NLL = (long)NB * LL * LL;  // 16,777,216

__device__ __forceinline__ u16 f2bf(float x) {
  u32 u = __float_as_uint(x);
  u += 0x7fffu + ((u >> 16) & 1u);
  return (u16)(u >> 16);
}
__device__ __forceinline__ float bf2f(u16 h) {
  return __uint_as_float((u32)h << 16);
}

// ---------------------------------------------------------------------------
// fp32 -> bf16 hi (+ optional lo residual) elementwise
// ---------------------------------------------------------------------------
template <bool SPLIT>
__global__ __launch_bounds__(256) void k_split(const float* __restrict__ x,
                                               u16* __restrict__ hi,
                                               u16* __restrict__ lo, long n) {
  const long stride = (long)gridDim.x * 1024;
  for (long i = ((long)blockIdx.x * 256 + threadIdx.x) * 4; i < n;
       i += stride) {
    const float4 v = *(const float4*)(x + i);
    ushort4 h;
    h.x = f2bf(v.x);
    h.y = f2bf(v.y);
    h.z = f2bf(v.z);
    h.w = f2bf(v.w);
    *(ushort4*)(hi + i) = h;
    if constexpr (SPLIT) {
      ushort4 s;
      s.x = f2bf(v.x - bf2f(h.x));
      s.y = f2bf(v.y - bf2f(h.y));
      s.z = f2bf(v.z - bf2f(h.z));
      s.w = f2bf(v.w - bf2f(h.w));
      *(ushort4*)(lo + i) = s;
    }
  }
}

// ---------------------------------------------------------------------------
// GEMM cores: 512 threads = 8 waves. BK=32. LDS tile rows are 64B (32 bf16);
// chunk swizzle c' = c ^ ((r>>1)&3); staging keeps LDS dest LINEAR and
// applies the inverse swizzle to the per-lane GLOBAL source.
// 2-phase schedule: prologue stages tile 0; loop iter t issues stage(t+1)
// FIRST, then ds_read+MFMA on tile t, then one __syncthreads (vmcnt drain +
// barrier). Load latency of t+1 hides under compute of t.
// ---------------------------------------------------------------------------
template <int NISS>
__device__ __forceinline__ void stage_tile(const u16* __restrict__ G, long ld,
                                           int row0, int k0, char* lds, int w,
                                           int l) {
#pragma unroll
  for (int i = 0; i < NISS; ++i) {
    const int off = i * 8192 + w * 1024 + l * 16;
    const int r = off >> 6;
    const int cp = (off >> 4) & 3;
    const int c = cp ^ ((r >> 1) & 3);
    __builtin_amdgcn_global_load_lds(
        (gptr_t)(G + (long)(row0 + r) * ld + k0 + c * 8),
        (sptr_t)(lds + i * 8192 + w * 1024), 16, 0, 0);
  }
}

__device__ __forceinline__ bf16x8 read_frag(const char* lds, int r, int ks) {
  const int cp = ks ^ ((r >> 1) & 3);
  return *(const bf16x8*)(lds + r * 64 + cp * 16);
}

// plain bf16 NT, 256x256 tile. Waves 2Mx4N: per-wave 128x64. LDS 2*32KB.
__device__ __forceinline__ void core_plain256(const u16* __restrict__ A,
                                              long lda,
                                              const u16* __restrict__ B,
                                              long ldb, int K, int bm, int bn,
                                              char* smem, f32x4 acc[8][4]) {
  const int tid = threadIdx.x, w = tid >> 6, l = tid & 63;
  const int wm = (w >> 2) * 128, wn = (w & 3) * 64;
  const int fr = l & 15, ks = l >> 4;
  const int nt = K / 32;
  stage_tile<2>(A, lda, bm, 0, smem, w, l);
  stage_tile<2>(B, ldb, bn, 0, smem + 16384, w, l);
  __syncthreads();
  for (int t = 0; t < nt; ++t) {
    char* cur = smem + (t & 1) * 32768;
    if (t + 1 < nt) {
      char* nxt = smem + ((t + 1) & 1) * 32768;
      stage_tile<2>(A, lda, bm, (t + 1) * 32, nxt, w, l);
      stage_tile<2>(B, ldb, bn, (t + 1) * 32, nxt + 16384, w, l);
    }
    bf16x8 af[8], bg[4];
#pragma unroll
    for (int mi = 0; mi < 8; ++mi)
      af[mi] = read_frag(cur, wm + mi * 16 + fr, ks);
#pragma unroll
    for (int ni = 0; ni < 4; ++ni)
      bg[ni] = read_frag(cur + 16384, wn + ni * 16 + fr, ks);
#pragma unroll
    for (int mi = 0; mi < 8; ++mi)
#pragma unroll
      for (int ni = 0; ni < 4; ++ni)
        acc[mi][ni] = __builtin_amdgcn_mfma_f32_16x16x32_bf16(
            af[mi], bg[ni], acc[mi][ni], 0, 0, 0);
    __syncthreads();
  }
}

// split bf16 NT, 256x256 tile: hh + hl + lh. LDS 2*64KB (dynamic 128KB).
__device__ __forceinline__ void core_split256(
    const u16* __restrict__ Ah, const u16* __restrict__ Al, long lda,
    const u16* __restrict__ Bh, const u16* __restrict__ Bl, long ldb, int K,
    int bm, int bn, char* smem, f32x4 acc[8][4]) {
  const int tid = threadIdx.x, w = tid >> 6, l = tid & 63;
  const int wm = (w >> 2) * 128, wn = (w & 3) * 64;
  const int fr = l & 15, ks = l >> 4;
  const int nt = K / 32;
  stage_tile<2>(Ah, lda, bm, 0, smem, w, l);
  stage_tile<2>(Bh, ldb, bn, 0, smem + 16384, w, l);
  stage_tile<2>(Al, lda, bm, 0, smem + 32768, w, l);
  stage_tile<2>(Bl, ldb, bn, 0, smem + 49152, w, l);
  __syncthreads();
  for (int t = 0; t < nt; ++t) {
    char* cur = smem + (t & 1) * 65536;
    if (t + 1 < nt) {
      char* nxt = smem + ((t + 1) & 1) * 65536;
      const int k1 = (t + 1) * 32;
      stage_tile<2>(Ah, lda, bm, k1, nxt, w, l);
      stage_tile<2>(Bh, ldb, bn, k1, nxt + 16384, w, l);
      stage_tile<2>(Al, lda, bm, k1, nxt + 32768, w, l);
      stage_tile<2>(Bl, ldb, bn, k1, nxt + 49152, w, l);
    }
    bf16x8 ah[8], bh[4];
#pragma unroll
    for (int mi = 0; mi < 8; ++mi)
      ah[mi] = read_frag(cur, wm + mi * 16 + fr, ks);
#pragma unroll
    for (int ni = 0; ni < 4; ++ni)
      bh[ni] = read_frag(cur + 16384, wn + ni * 16 + fr, ks);
#pragma unroll
    for (int mi = 0; mi < 8; ++mi)
#pragma unroll
      for (int ni = 0; ni < 4; ++ni)
        acc[mi][ni] = __builtin_amdgcn_mfma_f32_16x16x32_bf16(
            ah[mi], bh[ni], acc[mi][ni], 0, 0, 0);
    bf16x8 bl[4];
#pragma unroll
    for (int ni = 0; ni < 4; ++ni)
      bl[ni] = read_frag(cur + 49152, wn + ni * 16 + fr, ks);
#pragma unroll
    for (int mi = 0; mi < 8; ++mi)
#pragma unroll
      for (int ni = 0; ni < 4; ++ni)
        acc[mi][ni] = __builtin_amdgcn_mfma_f32_16x16x32_bf16(
            ah[mi], bl[ni], acc[mi][ni], 0, 0, 0);
    bf16x8 al[8];
#pragma unroll
    for (int mi = 0; mi < 8; ++mi)
      al[mi] = read_frag(cur + 32768, wm + mi * 16 + fr, ks);
#pragma unroll
    for (int mi = 0; mi < 8; ++mi)
#pragma unroll
      for (int ni = 0; ni < 4; ++ni)
        acc[mi][ni] = __builtin_amdgcn_mfma_f32_16x16x32_bf16(
            al[mi], bh[ni], acc[mi][ni], 0, 0, 0);
    __syncthreads();
  }
}

// plain bf16 NT, 128x256 tile. Waves 2Mx4N: per-wave 64x64. LDS 2*24KB.
__device__ __forceinline__ void core_plain128(const u16* __restrict__ A,
                                              long lda,
                                              const u16* __restrict__ B,
                                              long ldb, int K, int bm, int bn,
                                              char* smem, f32x4 acc[4][4]) {
  const int tid = threadIdx.x, w = tid >> 6, l = tid & 63;
  const int wm = (w >> 2) * 64, wn = (w & 3) * 64;
  const int fr = l & 15, ks = l >> 4;
  const int nt = K / 32;
  stage_tile<1>(A, lda, bm, 0, smem, w, l);
  stage_tile<2>(B, ldb, bn, 0, smem + 8192, w, l);
  __syncthreads();
  for (int t = 0; t < nt; ++t) {
    char* cur = smem + (t & 1) * 24576;
    if (t + 1 < nt) {
      char* nxt = smem + ((t + 1) & 1) * 24576;
      stage_tile<1>(A, lda, bm, (t + 1) * 32, nxt, w, l);
      stage_tile<2>(B, ldb, bn, (t + 1) * 32, nxt + 8192, w, l);
    }
    bf16x8 af[4], bg[4];
#pragma unroll
    for (int mi = 0; mi < 4; ++mi)
      af[mi] = read_frag(cur, wm + mi * 16 + fr, ks);
#pragma unroll
    for (int ni = 0; ni < 4; ++ni)
      bg[ni] = read_frag(cur + 8192, wn + ni * 16 + fr, ks);
#pragma unroll
    for (int mi = 0; mi < 4; ++mi)
#pragma unroll
      for (int ni = 0; ni < 4; ++ni)
        acc[mi][ni] = __builtin_amdgcn_mfma_f32_16x16x32_bf16(
            af[mi], bg[ni], acc[mi][ni], 0, 0, 0);
    __syncthreads();
  }
}

// C/D coords: row = bm + wm + mi*16 + ks*4 + j, col = bn + wn + ni*16 + fr
#define EPI_PROLOG()                                       \
  const int tid = threadIdx.x, w = tid >> 6, l = tid & 63; \
  const int wm = (w >> 2) * 128, wn = (w & 3) * 64;        \
  const int fr = l & 15, ks = l >> 4;

#define EPI_PROLOG128()                                    \
  const int tid = threadIdx.x, w = tid >> 6, l = tid & 63; \
  const int wm = (w >> 2) * 64, wn = (w & 3) * 64;         \
  const int fr = l & 15, ks = l >> 4;

// ---------------------------------------------------------------------------
// qp/kp/vp projections (plain), bf16 output. grid (2, 64, 3)
// ---------------------------------------------------------------------------
__global__ __launch_bounds__(512, 2) void k_proj_p(
    const u16* __restrict__ q_hi, const u16* __restrict__ k_hi,
    const u16* __restrict__ v_hi, const u16* __restrict__ Wq_h,
    const u16* __restrict__ Wk_h, const u16* __restrict__ Wv_h,
    u16* __restrict__ qp, u16* __restrict__ kp, u16* __restrict__ vp) {
  const u16 *A, *B;
  u16* C;
  switch (blockIdx.z) {
    case 0: A = q_hi; B = Wq_h; C = qp; break;
    case 1: A = k_hi; B = Wk_h; C = kp; break;
    default: A = v_hi; B = Wv_h; C = vp; break;
  }
  __shared__ __align__(16) char smem[65536];
  const int bm = blockIdx.y * 256, bn = blockIdx.x * 256;
  f32x4 acc[8][4] = {};
  core_plain256(A, DD, B, DD, DD, bm, bn, smem, acc);
  EPI_PROLOG()
#pragma unroll
  for (int mi = 0; mi < 8; ++mi) {
    const int R0 = bm + wm + mi * 16 + ks * 4;
#pragma unroll
    for (int ni = 0; ni < 4; ++ni) {
      const int col = bn + wn + ni * 16 + fr;
#pragma unroll
      for (int j = 0; j < 4; ++j)
        C[(long)(R0 + j) * DD + col] = f2bf(acc[mi][ni][j]);
    }
  }
}

// ---------------------------------------------------------------------------
// qt0/kt0 projections (split), fp32 output. grid (2, 64, 2), 128KB dyn LDS
// ---------------------------------------------------------------------------
__global__ __launch_bounds__(512, 2) void k_proj_t(
    const u16* __restrict__ q_hi, const u16* __restrict__ q_lo,
    const u16* __restrict__ k_hi, const u16* __restrict__ k_lo,
    const u16* __restrict__ Wqt_h, const u16* __restrict__ Wqt_l,
    const u16* __restrict__ Wkt_h, const u16* __restrict__ Wkt_l,
    float* __restrict__ qt0f, float* __restrict__ kt0f) {
  extern __shared__ __align__(16) char dsm[];
  const int sel = blockIdx.z;
  const u16* Ah = sel ? k_hi : q_hi;
  const u16* Al = sel ? k_lo : q_lo;
  const u16* Bh = sel ? Wkt_h : Wqt_h;
  const u16* Bl = sel ? Wkt_l : Wqt_l;
  float* C = sel ? kt0f : qt0f;
  const int bm = blockIdx.y * 256, bn = blockIdx.x * 256;
  f32x4 acc[8][4] = {};
  core_split256(Ah, Al, DD, Bh, Bl, DD, DD, bm, bn, dsm, acc);
  EPI_PROLOG()
#pragma unroll
  for (int mi = 0; mi < 8; ++mi) {
    const int R0 = bm + wm + mi * 16 + ks * 4;
#pragma unroll
    for (int ni = 0; ni < 4; ++ni) {
      const int col = bn + wn + ni * 16 + fr;
#pragma unroll
      for (int j = 0; j < 4; ++j)
        C[(long)(R0 + j) * DD + col] = acc[mi][ni][j];
    }
  }
}

// ---------------------------------------------------------------------------
// transpose + split: fp32 [1024][512] -> bf16 hi/lo [512][1024]
// ---------------------------------------------------------------------------
__global__ __launch_bounds__(256) void k_tsplit(
    const float* __restrict__ qt0, const float* __restrict__ kt0,
    u16* __restrict__ qT_h, u16* __restrict__ qT_l, u16* __restrict__ kT_h,
    u16* __restrict__ kT_l) {
  const int b = blockIdx.z >> 1, sel = blockIdx.z & 1;
  const float* X = (sel ? kt0 : qt0) + (long)b * LL * DD;
  u16* Oh = (sel ? kT_h : qT_h) + (long)b * LL * DD;
  u16* Ol = (sel ? kT_l : qT_l) + (long)b * LL * DD;
  __shared__ float t[64][65];
  const int r0 = blockIdx.y * 64, c0 = blockIdx.x * 64;
  const int tid = threadIdx.x;
#pragma unroll
  for (int i = 0; i < 16; ++i) {
    const int idx = tid + i * 256;
    t[idx >> 6][idx & 63] = X[(long)(r0 + (idx >> 6)) * DD + c0 + (idx & 63)];
  }
  __syncthreads();
#pragma unroll
  for (int i = 0; i < 16; ++i) {
    const int idx = tid + i * 256;
    const int rr = idx >> 6, cc = idx & 63;
    const float x = t[cc][rr];
    const u16 h = f2bf(x);
    Oh[(long)(c0 + rr) * LL + r0 + cc] = h;
    Ol[(long)(c0 + rr) * LL + r0 + cc] = f2bf(x - bf2f(h));
  }
}

// per-batch bf16 transpose: [1024][512] -> [512][1024] (vp -> vpT)
__global__ __launch_bounds__(256) void k_tbf16(const u16* __restrict__ X,
                                               u16* __restrict__ O) {
  const int b = blockIdx.z;
  const u16* Xb = X + (long)b * LL * DD;
  u16* Ob = O + (long)b * LL * DD;
  __shared__ u16 t[64][68];
  const int r0 = blockIdx.y * 64, c0 = blockIdx.x * 64;
  const int tid = threadIdx.x;
#pragma unroll
  for (int i = 0; i < 16; ++i) {
    const int idx = tid + i * 256;
    t[idx >> 6][idx & 63] = Xb[(long)(r0 + (idx >> 6)) * DD + c0 + (idx & 63)];
  }
  __syncthreads();
#pragma unroll
  for (int i = 0; i < 16; ++i) {
    const int idx = tid + i * 256;
    const int rr = idx >> 6, cc = idx & 63;
    Ob[(long)(c0 + rr) * LL + r0 + cc] = t[cc][rr];
  }
}

// ---------------------------------------------------------------------------
// distance matmuls (split): qt/kt = dist * {q,k}t0, split bf16 out.
// grid (2, 4, 32), 128KB dyn LDS
// ---------------------------------------------------------------------------
__global__ __launch_bounds__(512, 2) void k_dist_g(
    const u16* __restrict__ dist_h, const u16* __restrict__ dist_l,
    const u16* __restrict__ qT_h, const u16* __restrict__ qT_l,
    const u16* __restrict__ kT_h, const u16* __restrict__ kT_l,
    u16* __restrict__ qt_h, u16* __restrict__ qt_l, u16* __restrict__ kt_h,
    u16* __restrict__ kt_l) {
  extern __shared__ __align__(16) char dsm[];
  const int b = blockIdx.z >> 1, sel = blockIdx.z & 1;
  const u16* Ah = dist_h + (long)b * LL * LL;
  const u16* Al = dist_l + (long)b * LL * LL;
  const u16* Bh = (sel ? kT_h : qT_h) + (long)b * LL * DD;
  const u16* Bl = (sel ? kT_l : qT_l) + (long)b * LL * DD;
  u16* Oh = (sel ? kt_h : qt_h) + (long)b * LL * DD;
  u16* Ol = (sel ? kt_l : qt_l) + (long)b * LL * DD;
  const int bm = blockIdx.y * 256, bn = blockIdx.x * 256;
  f32x4 acc[8][4] = {};
  core_split256(Ah, Al, LL, Bh, Bl, LL, LL, bm, bn, dsm, acc);
  EPI_PROLOG()
#pragma unroll
  for (int mi = 0; mi < 8; ++mi) {
    const int R0 = bm + wm + mi * 16 + ks * 4;
#pragma unroll
    for (int ni = 0; ni < 4; ++ni) {
      const int col = bn + wn + ni * 16 + fr;
#pragma unroll
      for (int j = 0; j < 4; ++j) {
        const float x = acc[mi][ni][j];
        const u16 h = f2bf(x);
        Oh[(long)(R0 + j) * DD + col] = h;
        Ol[(long)(R0 + j) * DD + col] = f2bf(x - bf2f(h));
      }
    }
  }
}

// ---------------------------------------------------------------------------
// scores: split(qt,kt) + plain(qp,kp) -> mask+tanh -> attn fp32 + bf16
// grid (4, 4, 16), 128KB dyn LDS
// ---------------------------------------------------------------------------
__global__ __launch_bounds__(512, 2) void k_score(
    const u16* __restrict__ qp, const u16* __restrict__ kp,
    const u16* __restrict__ qt_h, const u16* __restrict__ qt_l,
    const u16* __restrict__ kt_h, const u16* __restrict__ kt_l,
    const int* __restrict__ lens, float* __restrict__ attnF,
    u16* __restrict__ attnB) {
  extern __shared__ __align__(16) char dsm[];
  const int b = blockIdx.z;
  const long od = (long)b * LL * DD;
  const int bm = blockIdx.y * 256, bn = blockIdx.x * 256;
  f32x4 acc[8][4] = {};
  core_split256(qt_h + od, qt_l + od, DD, kt_h + od, kt_l + od, DD, DD, bm, bn,
                dsm, acc);
  core_plain256(qp + od, DD, kp + od, DD, DD, bm, bn, dsm, acc);
  const int len = lens[b];
  const float invt = 0.04419417382415922f;  // 1/sqrt(512)
  EPI_PROLOG()
#pragma unroll
  for (int mi = 0; mi < 8; ++mi) {
    const int R0 = bm + wm + mi * 16 + ks * 4;
#pragma unroll
    for (int ni = 0; ni < 4; ++ni) {
      const int col = bn + wn + ni * 16 + fr;
      const float m = (col < len) ? 1.0f : 0.0f;
#pragma unroll
      for (int j = 0; j < 4; ++j) {
        const float s = tanhf(acc[mi][ni][j] * invt * m) * m;
        const long idx = (long)b * LL * LL + (long)(R0 + j) * LL + col;
        attnF[idx] = s;
        attnB[idx] = f2bf(s);
      }
    }
  }
}

// ---------------------------------------------------------------------------
// PV: out0 = attn * vp (plain 128x256 via vpT), bf16 out. grid (2, 8, 16)
// ---------------------------------------------------------------------------
__global__ __launch_bounds__(512, 2) void k_pv(const u16* __restrict__ attnB,
                                               const u16* __restrict__ vpT,
                                               u16* __restrict__ out0) {
  const int b = blockIdx.z;
  __shared__ __align__(16) char smem[49152];
  const int bm = blockIdx.y * 128, bn = blockIdx.x * 256;
  f32x4 acc[4][4] = {};
  core_plain128(attnB + (long)b * LL * LL, LL, vpT + (long)b * LL * DD, LL,
                LL, bm, bn, smem, acc);
  u16* C = out0 + (long)b * LL * DD;
  EPI_PROLOG128()
#pragma unroll
  for (int mi = 0; mi < 4; ++mi) {
    const int R0 = bm + wm + mi * 16 + ks * 4;
#pragma unroll
    for (int ni = 0; ni < 4; ++ni) {
      const int col = bn + wn + ni * 16 + fr;
#pragma unroll
      for (int j = 0; j < 4; ++j)
        C[(long)(R0 + j) * DD + col] = f2bf(acc[mi][ni][j]);
    }
  }
}

// ---------------------------------------------------------------------------
// FC + residual (plain 128x256), fp32 out. grid (2, 128)
// ---------------------------------------------------------------------------
__global__ __launch_bounds__(512, 2) void k_fc(const u16* __restrict__ out0,
                                               const u16* __restrict__ Wfc_h,
                                               const float* __restrict__ q,
                                               float* __restrict__ out1) {
  __shared__ __align__(16) char smem[49152];
  const int bm = blockIdx.y * 128, bn = blockIdx.x * 256;
  f32x4 acc[4][4] = {};
  core_plain128(out0, DD, Wfc_h, DD, DD, bm, bn, smem, acc);
  EPI_PROLOG128()
#pragma unroll
  for (int mi = 0; mi < 4; ++mi) {
    const int R0 = bm + wm + mi * 16 + ks * 4;
#pragma unroll
    for (int ni = 0; ni < 4; ++ni) {
      const int col = bn + wn + ni * 16 + fr;
#pragma unroll
      for (int j = 0; j < 4; ++j) {
        const long r = (long)(R0 + j) * DD + col;
        out1[r] = acc[mi][ni][j] + q[r];
      }
    }
  }
}

// ---------------------------------------------------------------------------
// LayerNorm over last dim (512)
// ---------------------------------------------------------------------------
__global__ __launch_bounds__(256) void k_ln(const float* __restrict__ x,
                                            const float* __restrict__ gamma,
                                            const float* __restrict__ beta,
                                            float* __restrict__ y) {
  const int r = blockIdx.x;
  const float* xr = x + (long)r * DD;
  const int t = threadIdx.x;
  const float x0 = xr[t], x1 = xr[t + 256];
  float s1 = x0 + x1;
  float s2 = x0 * x0 + x1 * x1;
#pragma unroll
  for (int off = 32; off; off >>= 1) {
    s1 += __shfl_down(s1, off);
    s2 += __shfl_down(s2, off);
  }
  __shared__ float r1[4], r2[4];
  __shared__ float smu, srs;
  if ((t & 63) == 0) {
    r1[t >> 6] = s1;
    r2[t >> 6] = s2;
  }
  __syncthreads();
  if (t == 0) {
    const float t1 = r1[0] + r1[1] + r1[2] + r1[3];
    const float t2 = r2[0] + r2[1] + r2[2] + r2[3];
    const float mu = t1 / (float)DD;
    smu = mu;
    srs = rsqrtf(t2 / (float)DD - mu * mu + 1e-6f);
  }
  __syncthreads();
  const float mu = smu, rs = srs;
  y[(long)r * DD + t] = (x0 - mu) * rs * gamma[t] + beta[t];
  y[(long)r * DD + t + 256] = (x1 - mu) * rs * gamma[t + 256] + beta[t + 256];
}

// ---------------------------------------------------------------------------
extern "C" void kernel_launch(void* const* d_in, const int* in_sizes, int n_in,
                              void* d_out, int out_size, void* d_ws,
                              size_t ws_size, hipStream_t stream) {
  const float* q = (const float*)d_in[0];
  const float* k = (const float*)d_in[1];
  const float* v = (const float*)d_in[2];
  const int* lens = (const int*)d_in[3];
  const float* dist = (const float*)d_in[4];
  const float* Wq = (const float*)d_in[5];
  const float* Wk = (const float*)d_in[6];
  const float* Wv = (const float*)d_in[7];
  const float* Wqt = (const float*)d_in[8];
  const float* Wkt = (const float*)d_in[9];
  const float* Wfc = (const float*)d_in[10];
  const float* gamma = (const float*)d_in[11];
  const float* beta = (const float*)d_in[12];

  // allow 128KB dynamic LDS on the split-core kernels (host-side, capture-safe)
  (void)hipFuncSetAttribute((const void*)k_proj_t,
                            hipFuncAttributeMaxDynamicSharedMemorySize, 131072);
  (void)hipFuncSetAttribute((const void*)k_dist_g,
                            hipFuncAttributeMaxDynamicSharedMemorySize, 131072);
  (void)hipFuncSetAttribute((const void*)k_score,
                            hipFuncAttributeMaxDynamicSharedMemorySize, 131072);

  char* W = (char*)d_ws;
  const size_t SB = 16777216;  // bytes of one bf16 [16384][512] buffer
  u16* q_hi = (u16*)(W + 0 * SB);    // reused later as qt_h
  u16* q_lo = (u16*)(W + 1 * SB);    // reused later as qt_l
  u16* k_hi = (u16*)(W + 2 * SB);    // reused later as kt_h
  u16* k_lo = (u16*)(W + 3 * SB);    // reused later as kt_l
  u16* v_hi = (u16*)(W + 4 * SB);    // reused later as vpT
  u16* dist_h = (u16*)(W + 5 * SB);  // 2SB; reused later as attnB
  u16* dist_l = (u16*)(W + 7 * SB);  // 2SB
  u16* qp_bf = (u16*)(W + 9 * SB);   // reused later as out0
  u16* kp_bf = (u16*)(W + 10 * SB);
  u16* vp_bf = (u16*)(W + 11 * SB);
  float* qt0f = (float*)(W + 12 * SB);  // 2SB; reused later as out1
  float* kt0f = (float*)(W + 14 * SB);  // 2SB
  u16* qT_h = (u16*)(W + 16 * SB);
  u16* qT_l = (u16*)(W + 17 * SB);
  u16* kT_h = (u16*)(W + 18 * SB);
  u16* kT_l = (u16*)(W + 19 * SB);
  char* WB = W + 20 * SB;
  const size_t WS = 524288;
  u16* Wq_h = (u16*)(WB + 0 * WS);
  u16* Wk_h = (u16*)(WB + 1 * WS);
  u16* Wv_h = (u16*)(WB + 2 * WS);
  u16* Wfc_h = (u16*)(WB + 3 * WS);
  u16* Wqt_h = (u16*)(WB + 4 * WS);
  u16* Wqt_l = (u16*)(WB + 5 * WS);
  u16* Wkt_h = (u16*)(WB + 6 * WS);
  u16* Wkt_l = (u16*)(WB + 7 * WS);
  // aliases (lifetimes disjoint, stream-ordered)
  u16* qt_h = q_hi;
  u16* qt_l = q_lo;
  u16* kt_h = k_hi;
  u16* kt_l = k_lo;
  u16* vpT = v_hi;
  u16* attnB = dist_h;
  u16* out0 = qp_bf;
  float* out1 = qt0f;

  float* outO = (float*)d_out;
  float* attnF = outO + NLD;

  dim3 b256(256), b512(512);
  k_split<true><<<4096, b256, 0, stream>>>(q, q_hi, q_lo, NLD);
  k_split<true><<<4096, b256, 0, stream>>>(k, k_hi, k_lo, NLD);
  k_split<false><<<4096, b256, 0, stream>>>(v, v_hi, nullptr, NLD);
  k_split<true><<<4096, b256, 0, stream>>>(dist, dist_h, dist_l, NLL);
  k_split<false><<<256, b256, 0, stream>>>(Wq, Wq_h, nullptr, 262144);
  k_split<false><<<256, b256, 0, stream>>>(Wk, Wk_h, nullptr, 262144);
  k_split<false><<<256, b256, 0, stream>>>(Wv, Wv_h, nullptr, 262144);
  k_split<false><<<256, b256, 0, stream>>>(Wfc, Wfc_h, nullptr, 262144);
  k_split<true><<<256, b256, 0, stream>>>(Wqt, Wqt_h, Wqt_l, 262144);
  k_split<true><<<256, b256, 0, stream>>>(Wkt, Wkt_h, Wkt_l, 262144);

  k_proj_p<<<dim3(2, 64, 3), b512, 0, stream>>>(q_hi, k_hi, v_hi, Wq_h, Wk_h,
                                                Wv_h, qp_bf, kp_bf, vp_bf);
  k_proj_t<<<dim3(2, 64, 2), b512, 131072, stream>>>(
      q_hi, q_lo, k_hi, k_lo, Wqt_h, Wqt_l, Wkt_h, Wkt_l, qt0f, kt0f);
  k_tsplit<<<dim3(8, 16, 32), b256, 0, stream>>>(qt0f, kt0f, qT_h, qT_l, kT_h,
                                                 kT_l);
  k_tbf16<<<dim3(8, 16, 16), b256, 0, stream>>>(vp_bf, vpT);
  k_dist_g<<<dim3(2, 4, 32), b512, 131072, stream>>>(
      dist_h, dist_l, qT_h, qT_l, kT_h, kT_l, qt_h, qt_l, kt_h, kt_l);
  k_score<<<dim3(4, 4, 16), b512, 131072, stream>>>(qp_bf, kp_bf, qt_h, qt_l,
                                                    kt_h, kt_l, lens, attnF,
                                                    attnB);
  k_pv<<<dim3(2, 8, 16), b512, 0, stream>>>(attnB, vpT, out0);
  k_fc<<<dim3(2, 128, 1), b512, 0, stream>>>(out0, Wfc_h, q, out1);
  k_ln<<<NB * LL, b256, 0, stream>>>(out1, gamma, beta, outO);
}

// Round 4
// 590.777 us; speedup vs baseline: 1.0645x; 1.0645x over previous
//
#include <hip/hip_runtime.h>
#include <math.h>

#define LL 1024
#define DD 512
#define NB 16

typedef __attribute__((ext_vector_type(8))) short bf16x8;
typedef __attribute__((ext_vector_type(4))) float f32x4;
typedef unsigned short u16;
typedef unsigned int u32;
typedef const __attribute__((address_space(1))) void* gptr_t;
typedef __attribute__((address_space(3))) void* sptr_t;

static const long NLD = (long)NB * LL * DD;  // 8,388,608
static const long NLL = (long)NB * LL * LL;  // 16,777,216

__device__ __forceinline__ u16 f2bf(float x) {
  u32 u = __float_as_uint(x);
  u += 0x7fffu + ((u >> 16) & 1u);
  return (u16)(u >> 16);
}
__device__ __forceinline__ float bf2f(u16 h) {
  return __uint_as_float((u32)h << 16);
}

// ---------------------------------------------------------------------------
// fp32 -> bf16 hi (+ optional lo residual) elementwise
// ---------------------------------------------------------------------------
template <bool SPLIT>
__global__ __launch_bounds__(256) void k_split(const float* __restrict__ x,
                                               u16* __restrict__ hi,
                                               u16* __restrict__ lo, long n) {
  const long stride = (long)gridDim.x * 1024;
  for (long i = ((long)blockIdx.x * 256 + threadIdx.x) * 4; i < n;
       i += stride) {
    const float4 v = *(const float4*)(x + i);
    ushort4 h;
    h.x = f2bf(v.x);
    h.y = f2bf(v.y);
    h.z = f2bf(v.z);
    h.w = f2bf(v.w);
    *(ushort4*)(hi + i) = h;
    if constexpr (SPLIT) {
      ushort4 s;
      s.x = f2bf(v.x - bf2f(h.x));
      s.y = f2bf(v.y - bf2f(h.y));
      s.z = f2bf(v.z - bf2f(h.z));
      s.w = f2bf(v.w - bf2f(h.w));
      *(ushort4*)(lo + i) = s;
    }
  }
}

// ---------------------------------------------------------------------------
// GEMM cores: 512 threads = 8 waves, counted-vmcnt double-buffered schedule.
// LDS operand tiles: R rows x 32 bf16 cols (64B rows); chunk-XOR swizzle
// cp = ks ^ ((r>>1)&3) on reads; staging keeps LDS dest LINEAR and applies
// the inverse swizzle to the per-lane GLOBAL source (measured: 0 conflicts).
//
// Per K-step t: STAGE(t+1) -> s_waitcnt vmcnt(N) [N = loads of t+1, so only
// t's loads drain; t+1's stay in flight ACROSS the barrier] -> s_barrier ->
// ds_read -> setprio(1) MFMA setprio(0) -> s_barrier [read-done guard].
// vmcnt never 0 mid-loop (T4); raw barriers, no compiler drain.
// ---------------------------------------------------------------------------
template <int ROWS>  // 256 or 128
__device__ __forceinline__ void stage32(const u16* __restrict__ G, long ld,
                                        int row0, int k0, char* lds, int w,
                                        int l) {
#pragma unroll
  for (int i = 0; i < ROWS / 128; ++i) {
    const int off = i * 8192 + w * 1024 + l * 16;
    const int r = off >> 6;
    const int cp = (off >> 4) & 3;
    const int c = cp ^ ((r >> 1) & 3);
    __builtin_amdgcn_global_load_lds(
        (gptr_t)(G + (long)(row0 + r) * ld + k0 + c * 8),
        (sptr_t)(lds + i * 8192 + w * 1024), 16, 0, 0);
  }
}

__device__ __forceinline__ bf16x8 read_frag(const char* lds, int r, int ks) {
  const int cp = ks ^ ((r >> 1) & 3);
  return *(const bf16x8*)(lds + r * 64 + cp * 16);
}

// split bf16 NT (hh+hl+lh), 256x256 tile, BK=32. Set = 64KB, dbuf = 128KB.
// 8 loads/thread/set -> vmcnt(8).
__device__ __forceinline__ void core_split256(
    const u16* __restrict__ Ah, const u16* __restrict__ Al, long lda,
    const u16* __restrict__ Bh, const u16* __restrict__ Bl, long ldb, int K,
    int bm, int bn, char* smem, f32x4 acc[8][4]) {
  const int tid = threadIdx.x, w = tid >> 6, l = tid & 63;
  const int wm = (w >> 2) * 128, wn = (w & 3) * 64;
  const int fr = l & 15, ks = l >> 4;
  const int nt = K / 32;
  __syncthreads();  // core entry: prior LDS users done
  {
    char* s = smem;
    stage32<256>(Ah, lda, bm, 0, s, w, l);
    stage32<256>(Bh, ldb, bn, 0, s + 16384, w, l);
    stage32<256>(Al, lda, bm, 0, s + 32768, w, l);
    stage32<256>(Bl, ldb, bn, 0, s + 49152, w, l);
  }
  for (int t = 0; t < nt; ++t) {
    if (t + 1 < nt) {
      char* s = smem + ((t + 1) & 1) * 65536;
      const int k1 = (t + 1) * 32;
      stage32<256>(Ah, lda, bm, k1, s, w, l);
      stage32<256>(Bh, ldb, bn, k1, s + 16384, w, l);
      stage32<256>(Al, lda, bm, k1, s + 32768, w, l);
      stage32<256>(Bl, ldb, bn, k1, s + 49152, w, l);
      asm volatile("s_waitcnt vmcnt(8)" ::: "memory");
    } else {
      asm volatile("s_waitcnt vmcnt(0)" ::: "memory");
    }
    __builtin_amdgcn_s_barrier();
    __builtin_amdgcn_sched_barrier(0);
    const char* cur = smem + (t & 1) * 65536;
    bf16x8 ah[8], bh[4];
#pragma unroll
    for (int mi = 0; mi < 8; ++mi)
      ah[mi] = read_frag(cur, wm + mi * 16 + fr, ks);
#pragma unroll
    for (int ni = 0; ni < 4; ++ni)
      bh[ni] = read_frag(cur + 16384, wn + ni * 16 + fr, ks);
    __builtin_amdgcn_s_setprio(1);
#pragma unroll
    for (int mi = 0; mi < 8; ++mi)
#pragma unroll
      for (int ni = 0; ni < 4; ++ni)
        acc[mi][ni] = __builtin_amdgcn_mfma_f32_16x16x32_bf16(
            ah[mi], bh[ni], acc[mi][ni], 0, 0, 0);
    __builtin_amdgcn_s_setprio(0);
    bf16x8 bl[4];
#pragma unroll
    for (int ni = 0; ni < 4; ++ni)
      bl[ni] = read_frag(cur + 49152, wn + ni * 16 + fr, ks);
    __builtin_amdgcn_s_setprio(1);
#pragma unroll
    for (int mi = 0; mi < 8; ++mi)
#pragma unroll
      for (int ni = 0; ni < 4; ++ni)
        acc[mi][ni] = __builtin_amdgcn_mfma_f32_16x16x32_bf16(
            ah[mi], bl[ni], acc[mi][ni], 0, 0, 0);
    __builtin_amdgcn_s_setprio(0);
    bf16x8 al[8];
#pragma unroll
    for (int mi = 0; mi < 8; ++mi)
      al[mi] = read_frag(cur + 32768, wm + mi * 16 + fr, ks);
    __builtin_amdgcn_s_setprio(1);
#pragma unroll
    for (int mi = 0; mi < 8; ++mi)
#pragma unroll
      for (int ni = 0; ni < 4; ++ni)
        acc[mi][ni] = __builtin_amdgcn_mfma_f32_16x16x32_bf16(
            al[mi], bh[ni], acc[mi][ni], 0, 0, 0);
    __builtin_amdgcn_s_setprio(0);
    __builtin_amdgcn_sched_barrier(0);
    __builtin_amdgcn_s_barrier();  // read-done guard for buffer reuse
  }
}

// plain bf16 NT, BMF x 256 tile, BK=64 (2 k-slabs of 32).
// BMF=256: set 64KB, 8 loads/thread -> vmcnt(8). BMF=128: set 48KB, 6 loads
// -> vmcnt(6). acc is [BMF/32][4].
template <int BMF>
__device__ __forceinline__ void core_plain(const u16* __restrict__ A, long lda,
                                           const u16* __restrict__ B, long ldb,
                                           int K, int bm, int bn, char* smem,
                                           f32x4 (*acc)[4]) {
  constexpr int AM = BMF / 32;
  constexpr int ASZ = BMF * 64;          // bytes per A k-slab
  constexpr int SET = 2 * ASZ + 32768;   // A0,A1,B0,B1
  const int tid = threadIdx.x, w = tid >> 6, l = tid & 63;
  const int wm = (w >> 2) * (BMF / 2), wn = (w & 3) * 64;
  const int fr = l & 15, ks = l >> 4;
  const int nt = K / 64;
  __syncthreads();  // core entry: prior LDS users done
  {
    char* s = smem;
    stage32<BMF>(A, lda, bm, 0, s, w, l);
    stage32<BMF>(A, lda, bm, 32, s + ASZ, w, l);
    stage32<256>(B, ldb, bn, 0, s + 2 * ASZ, w, l);
    stage32<256>(B, ldb, bn, 32, s + 2 * ASZ + 16384, w, l);
  }
  for (int t = 0; t < nt; ++t) {
    if (t + 1 < nt) {
      char* s = smem + ((t + 1) & 1) * SET;
      const int k1 = (t + 1) * 64;
      stage32<BMF>(A, lda, bm, k1, s, w, l);
      stage32<BMF>(A, lda, bm, k1 + 32, s + ASZ, w, l);
      stage32<256>(B, ldb, bn, k1, s + 2 * ASZ, w, l);
      stage32<256>(B, ldb, bn, k1 + 32, s + 2 * ASZ + 16384, w, l);
      if constexpr (BMF == 256) {
        asm volatile("s_waitcnt vmcnt(8)" ::: "memory");
      } else {
        asm volatile("s_waitcnt vmcnt(6)" ::: "memory");
      }
    } else {
      asm volatile("s_waitcnt vmcnt(0)" ::: "memory");
    }
    __builtin_amdgcn_s_barrier();
    __builtin_amdgcn_sched_barrier(0);
    const char* cur = smem + (t & 1) * SET;
#pragma unroll
    for (int s2 = 0; s2 < 2; ++s2) {
      const char* As = cur + s2 * ASZ;
      const char* Bs = cur + 2 * ASZ + s2 * 16384;
      bf16x8 af[AM], bg[4];
#pragma unroll
      for (int mi = 0; mi < AM; ++mi)
        af[mi] = read_frag(As, wm + mi * 16 + fr, ks);
#pragma unroll
      for (int ni = 0; ni < 4; ++ni)
        bg[ni] = read_frag(Bs, wn + ni * 16 + fr, ks);
      __builtin_amdgcn_s_setprio(1);
#pragma unroll
      for (int mi = 0; mi < AM; ++mi)
#pragma unroll
        for (int ni = 0; ni < 4; ++ni)
          acc[mi][ni] = __builtin_amdgcn_mfma_f32_16x16x32_bf16(
              af[mi], bg[ni], acc[mi][ni], 0, 0, 0);
      __builtin_amdgcn_s_setprio(0);
    }
    __builtin_amdgcn_sched_barrier(0);
    __builtin_amdgcn_s_barrier();  // read-done guard for buffer reuse
  }
}

// C/D coords: row = bm + wm + mi*16 + ks*4 + j, col = bn + wn + ni*16 + fr
#define EPI_PROLOG()                                       \
  const int tid = threadIdx.x, w = tid >> 6, l = tid & 63; \
  const int wm = (w >> 2) * 128, wn = (w & 3) * 64;        \
  const int fr = l & 15, ks = l >> 4;

#define EPI_PROLOG128()                                    \
  const int tid = threadIdx.x, w = tid >> 6, l = tid & 63; \
  const int wm = (w >> 2) * 64, wn = (w & 3) * 64;         \
  const int fr = l & 15, ks = l >> 4;

// ---------------------------------------------------------------------------
// qp/kp/vp projections (plain 256x256), bf16 out. grid (2, 64, 3), 128KB dyn
// ---------------------------------------------------------------------------
__global__ __launch_bounds__(512, 2) void k_proj_p(
    const u16* __restrict__ q_hi, const u16* __restrict__ k_hi,
    const u16* __restrict__ v_hi, const u16* __restrict__ Wq_h,
    const u16* __restrict__ Wk_h, const u16* __restrict__ Wv_h,
    u16* __restrict__ qp, u16* __restrict__ kp, u16* __restrict__ vp) {
  extern __shared__ __align__(16) char dsm[];
  const u16 *A, *B;
  u16* C;
  switch (blockIdx.z) {
    case 0: A = q_hi; B = Wq_h; C = qp; break;
    case 1: A = k_hi; B = Wk_h; C = kp; break;
    default: A = v_hi; B = Wv_h; C = vp; break;
  }
  const int bm = blockIdx.y * 256, bn = blockIdx.x * 256;
  f32x4 acc[8][4] = {};
  core_plain<256>(A, DD, B, DD, DD, bm, bn, dsm, acc);
  EPI_PROLOG()
#pragma unroll
  for (int mi = 0; mi < 8; ++mi) {
    const int R0 = bm + wm + mi * 16 + ks * 4;
#pragma unroll
    for (int ni = 0; ni < 4; ++ni) {
      const int col = bn + wn + ni * 16 + fr;
#pragma unroll
      for (int j = 0; j < 4; ++j)
        C[(long)(R0 + j) * DD + col] = f2bf(acc[mi][ni][j]);
    }
  }
}

// ---------------------------------------------------------------------------
// qt0/kt0 projections (split), fp32 out. grid (2, 64, 2), 128KB dyn
// ---------------------------------------------------------------------------
__global__ __launch_bounds__(512, 2) void k_proj_t(
    const u16* __restrict__ q_hi, const u16* __restrict__ q_lo,
    const u16* __restrict__ k_hi, const u16* __restrict__ k_lo,
    const u16* __restrict__ Wqt_h, const u16* __restrict__ Wqt_l,
    const u16* __restrict__ Wkt_h, const u16* __restrict__ Wkt_l,
    float* __restrict__ qt0f, float* __restrict__ kt0f) {
  extern __shared__ __align__(16) char dsm[];
  const int sel = blockIdx.z;
  const u16* Ah = sel ? k_hi : q_hi;
  const u16* Al = sel ? k_lo : q_lo;
  const u16* Bh = sel ? Wkt_h : Wqt_h;
  const u16* Bl = sel ? Wkt_l : Wqt_l;
  float* C = sel ? kt0f : qt0f;
  const int bm = blockIdx.y * 256, bn = blockIdx.x * 256;
  f32x4 acc[8][4] = {};
  core_split256(Ah, Al, DD, Bh, Bl, DD, DD, bm, bn, dsm, acc);
  EPI_PROLOG()
#pragma unroll
  for (int mi = 0; mi < 8; ++mi) {
    const int R0 = bm + wm + mi * 16 + ks * 4;
#pragma unroll
    for (int ni = 0; ni < 4; ++ni) {
      const int col = bn + wn + ni * 16 + fr;
#pragma unroll
      for (int j = 0; j < 4; ++j)
        C[(long)(R0 + j) * DD + col] = acc[mi][ni][j];
    }
  }
}

// ---------------------------------------------------------------------------
// transpose + split: fp32 [1024][512] -> bf16 hi/lo [512][1024]
// ---------------------------------------------------------------------------
__global__ __launch_bounds__(256) void k_tsplit(
    const float* __restrict__ qt0, const float* __restrict__ kt0,
    u16* __restrict__ qT_h, u16* __restrict__ qT_l, u16* __restrict__ kT_h,
    u16* __restrict__ kT_l) {
  const int b = blockIdx.z >> 1, sel = blockIdx.z & 1;
  const float* X = (sel ? kt0 : qt0) + (long)b * LL * DD;
  u16* Oh = (sel ? kT_h : qT_h) + (long)b * LL * DD;
  u16* Ol = (sel ? kT_l : qT_l) + (long)b * LL * DD;
  __shared__ float t[64][65];
  const int r0 = blockIdx.y * 64, c0 = blockIdx.x * 64;
  const int tid = threadIdx.x;
#pragma unroll
  for (int i = 0; i < 16; ++i) {
    const int idx = tid + i * 256;
    t[idx >> 6][idx & 63] = X[(long)(r0 + (idx >> 6)) * DD + c0 + (idx & 63)];
  }
  __syncthreads();
#pragma unroll
  for (int i = 0; i < 16; ++i) {
    const int idx = tid + i * 256;
    const int rr = idx >> 6, cc = idx & 63;
    const float x = t[cc][rr];
    const u16 h = f2bf(x);
    Oh[(long)(c0 + rr) * LL + r0 + cc] = h;
    Ol[(long)(c0 + rr) * LL + r0 + cc] = f2bf(x - bf2f(h));
  }
}

// per-batch bf16 transpose: [1024][512] -> [512][1024] (vp -> vpT)
__global__ __launch_bounds__(256) void k_tbf16(const u16* __restrict__ X,
                                               u16* __restrict__ O) {
  const int b = blockIdx.z;
  const u16* Xb = X + (long)b * LL * DD;
  u16* Ob = O + (long)b * LL * DD;
  __shared__ u16 t[64][68];
  const int r0 = blockIdx.y * 64, c0 = blockIdx.x * 64;
  const int tid = threadIdx.x;
#pragma unroll
  for (int i = 0; i < 16; ++i) {
    const int idx = tid + i * 256;
    t[idx >> 6][idx & 63] = Xb[(long)(r0 + (idx >> 6)) * DD + c0 + (idx & 63)];
  }
  __syncthreads();
#pragma unroll
  for (int i = 0; i < 16; ++i) {
    const int idx = tid + i * 256;
    const int rr = idx >> 6, cc = idx & 63;
    Ob[(long)(c0 + rr) * LL + r0 + cc] = t[cc][rr];
  }
}

// ---------------------------------------------------------------------------
// distance matmuls (split): qt/kt = dist * {q,k}t0, split bf16 out.
// grid (2, 4, 32), 128KB dyn
// ---------------------------------------------------------------------------
__global__ __launch_bounds__(512, 2) void k_dist_g(
    const u16* __restrict__ dist_h, const u16* __restrict__ dist_l,
    const u16* __restrict__ qT_h, const u16* __restrict__ qT_l,
    const u16* __restrict__ kT_h, const u16* __restrict__ kT_l,
    u16* __restrict__ qt_h, u16* __restrict__ qt_l, u16* __restrict__ kt_h,
    u16* __restrict__ kt_l) {
  extern __shared__ __align__(16) char dsm[];
  const int b = blockIdx.z >> 1, sel = blockIdx.z & 1;
  const u16* Ah = dist_h + (long)b * LL * LL;
  const u16* Al = dist_l + (long)b * LL * LL;
  const u16* Bh = (sel ? kT_h : qT_h) + (long)b * LL * DD;
  const u16* Bl = (sel ? kT_l : qT_l) + (long)b * LL * DD;
  u16* Oh = (sel ? kt_h : qt_h) + (long)b * LL * DD;
  u16* Ol = (sel ? kt_l : qt_l) + (long)b * LL * DD;
  const int bm = blockIdx.y * 256, bn = blockIdx.x * 256;
  f32x4 acc[8][4] = {};
  core_split256(Ah, Al, LL, Bh, Bl, LL, LL, bm, bn, dsm, acc);
  EPI_PROLOG()
#pragma unroll
  for (int mi = 0; mi < 8; ++mi) {
    const int R0 = bm + wm + mi * 16 + ks * 4;
#pragma unroll
    for (int ni = 0; ni < 4; ++ni) {
      const int col = bn + wn + ni * 16 + fr;
#pragma unroll
      for (int j = 0; j < 4; ++j) {
        const float x = acc[mi][ni][j];
        const u16 h = f2bf(x);
        Oh[(long)(R0 + j) * DD + col] = h;
        Ol[(long)(R0 + j) * DD + col] = f2bf(x - bf2f(h));
      }
    }
  }
}

// ---------------------------------------------------------------------------
// scores: split(qt,kt) + plain(qp,kp) -> mask+tanh -> attn fp32 + bf16
// grid (4, 4, 16), 128KB dyn
// ---------------------------------------------------------------------------
__global__ __launch_bounds__(512, 2) void k_score(
    const u16* __restrict__ qp, const u16* __restrict__ kp,
    const u16* __restrict__ qt_h, const u16* __restrict__ qt_l,
    const u16* __restrict__ kt_h, const u16* __restrict__ kt_l,
    const int* __restrict__ lens, float* __restrict__ attnF,
    u16* __restrict__ attnB) {
  extern __shared__ __align__(16) char dsm[];
  const int b = blockIdx.z;
  const long od = (long)b * LL * DD;
  const int bm = blockIdx.y * 256, bn = blockIdx.x * 256;
  f32x4 acc[8][4] = {};
  core_split256(qt_h + od, qt_l + od, DD, kt_h + od, kt_l + od, DD, DD, bm, bn,
                dsm, acc);
  core_plain<256>(qp + od, DD, kp + od, DD, DD, bm, bn, dsm, acc);
  const int len = lens[b];
  const float invt = 0.04419417382415922f;  // 1/sqrt(512)
  EPI_PROLOG()
#pragma unroll
  for (int mi = 0; mi < 8; ++mi) {
    const int R0 = bm + wm + mi * 16 + ks * 4;
#pragma unroll
    for (int ni = 0; ni < 4; ++ni) {
      const int col = bn + wn + ni * 16 + fr;
      const float m = (col < len) ? 1.0f : 0.0f;
#pragma unroll
      for (int j = 0; j < 4; ++j) {
        const float s = tanhf(acc[mi][ni][j] * invt * m) * m;
        const long idx = (long)b * LL * LL + (long)(R0 + j) * LL + col;
        attnF[idx] = s;
        attnB[idx] = f2bf(s);
      }
    }
  }
}

// ---------------------------------------------------------------------------
// PV: out0 = attn * vp (plain 128x256 via vpT), bf16 out. grid (2, 8, 16)
// ---------------------------------------------------------------------------
__global__ __launch_bounds__(512, 2) void k_pv(const u16* __restrict__ attnB,
                                               const u16* __restrict__ vpT,
                                               u16* __restrict__ out0) {
  extern __shared__ __align__(16) char dsm[];
  const int b = blockIdx.z;
  const int bm = blockIdx.y * 128, bn = blockIdx.x * 256;
  f32x4 acc[4][4] = {};
  core_plain<128>(attnB + (long)b * LL * LL, LL, vpT + (long)b * LL * DD, LL,
                  LL, bm, bn, dsm, acc);
  u16* C = out0 + (long)b * LL * DD;
  EPI_PROLOG128()
#pragma unroll
  for (int mi = 0; mi < 4; ++mi) {
    const int R0 = bm + wm + mi * 16 + ks * 4;
#pragma unroll
    for (int ni = 0; ni < 4; ++ni) {
      const int col = bn + wn + ni * 16 + fr;
#pragma unroll
      for (int j = 0; j < 4; ++j)
        C[(long)(R0 + j) * DD + col] = f2bf(acc[mi][ni][j]);
    }
  }
}

// ---------------------------------------------------------------------------
// FC + residual (plain 128x256), fp32 out. grid (2, 128)
// ---------------------------------------------------------------------------
__global__ __launch_bounds__(512, 2) void k_fc(const u16* __restrict__ out0,
                                               const u16* __restrict__ Wfc_h,
                                               const float* __restrict__ q,
                                               float* __restrict__ out1) {
  extern __shared__ __align__(16) char dsm[];
  const int bm = blockIdx.y * 128, bn = blockIdx.x * 256;
  f32x4 acc[4][4] = {};
  core_plain<128>(out0, DD, Wfc_h, DD, DD, bm, bn, dsm, acc);
  EPI_PROLOG128()
#pragma unroll
  for (int mi = 0; mi < 4; ++mi) {
    const int R0 = bm + wm + mi * 16 + ks * 4;
#pragma unroll
    for (int ni = 0; ni < 4; ++ni) {
      const int col = bn + wn + ni * 16 + fr;
#pragma unroll
      for (int j = 0; j < 4; ++j) {
        const long r = (long)(R0 + j) * DD + col;
        out1[r] = acc[mi][ni][j] + q[r];
      }
    }
  }
}

// ---------------------------------------------------------------------------
// LayerNorm over last dim (512)
// ---------------------------------------------------------------------------
__global__ __launch_bounds__(256) void k_ln(const float* __restrict__ x,
                                            const float* __restrict__ gamma,
                                            const float* __restrict__ beta,
                                            float* __restrict__ y) {
  const int r = blockIdx.x;
  const float* xr = x + (long)r * DD;
  const int t = threadIdx.x;
  const float x0 = xr[t], x1 = xr[t + 256];
  float s1 = x0 + x1;
  float s2 = x0 * x0 + x1 * x1;
#pragma unroll
  for (int off = 32; off; off >>= 1) {
    s1 += __shfl_down(s1, off);
    s2 += __shfl_down(s2, off);
  }
  __shared__ float r1[4], r2[4];
  __shared__ float smu, srs;
  if ((t & 63) == 0) {
    r1[t >> 6] = s1;
    r2[t >> 6] = s2;
  }
  __syncthreads();
  if (t == 0) {
    const float t1 = r1[0] + r1[1] + r1[2] + r1[3];
    const float t2 = r2[0] + r2[1] + r2[2] + r2[3];
    const float mu = t1 / (float)DD;
    smu = mu;
    srs = rsqrtf(t2 / (float)DD - mu * mu + 1e-6f);
  }
  __syncthreads();
  const float mu = smu, rs = srs;
  y[(long)r * DD + t] = (x0 - mu) * rs * gamma[t] + beta[t];
  y[(long)r * DD + t + 256] = (x1 - mu) * rs * gamma[t + 256] + beta[t + 256];
}

// ---------------------------------------------------------------------------
extern "C" void kernel_launch(void* const* d_in, const int* in_sizes, int n_in,
                              void* d_out, int out_size, void* d_ws,
                              size_t ws_size, hipStream_t stream) {
  const float* q = (const float*)d_in[0];
  const float* k = (const float*)d_in[1];
  const float* v = (const float*)d_in[2];
  const int* lens = (const int*)d_in[3];
  const float* dist = (const float*)d_in[4];
  const float* Wq = (const float*)d_in[5];
  const float* Wk = (const float*)d_in[6];
  const float* Wv = (const float*)d_in[7];
  const float* Wqt = (const float*)d_in[8];
  const float* Wkt = (const float*)d_in[9];
  const float* Wfc = (const float*)d_in[10];
  const float* gamma = (const float*)d_in[11];
  const float* beta = (const float*)d_in[12];

  // allow big dynamic LDS (host-side, capture-safe)
  (void)hipFuncSetAttribute((const void*)k_proj_p,
                            hipFuncAttributeMaxDynamicSharedMemorySize, 131072);
  (void)hipFuncSetAttribute((const void*)k_proj_t,
                            hipFuncAttributeMaxDynamicSharedMemorySize, 131072);
  (void)hipFuncSetAttribute((const void*)k_dist_g,
                            hipFuncAttributeMaxDynamicSharedMemorySize, 131072);
  (void)hipFuncSetAttribute((const void*)k_score,
                            hipFuncAttributeMaxDynamicSharedMemorySize, 131072);
  (void)hipFuncSetAttribute((const void*)k_pv,
                            hipFuncAttributeMaxDynamicSharedMemorySize, 98304);
  (void)hipFuncSetAttribute((const void*)k_fc,
                            hipFuncAttributeMaxDynamicSharedMemorySize, 98304);

  char* W = (char*)d_ws;
  const size_t SB = 16777216;  // bytes of one bf16 [16384][512] buffer
  u16* q_hi = (u16*)(W + 0 * SB);    // reused later as qt_h
  u16* q_lo = (u16*)(W + 1 * SB);    // reused later as qt_l
  u16* k_hi = (u16*)(W + 2 * SB);    // reused later as kt_h
  u16* k_lo = (u16*)(W + 3 * SB);    // reused later as kt_l
  u16* v_hi = (u16*)(W + 4 * SB);    // reused later as vpT
  u16* dist_h = (u16*)(W + 5 * SB);  // 2SB; reused later as attnB
  u16* dist_l = (u16*)(W + 7 * SB);  // 2SB
  u16* qp_bf = (u16*)(W + 9 * SB);   // reused later as out0
  u16* kp_bf = (u16*)(W + 10 * SB);
  u16* vp_bf = (u16*)(W + 11 * SB);
  float* qt0f = (float*)(W + 12 * SB);  // 2SB; reused later as out1
  float* kt0f = (float*)(W + 14 * SB);  // 2SB
  u16* qT_h = (u16*)(W + 16 * SB);
  u16* qT_l = (u16*)(W + 17 * SB);
  u16* kT_h = (u16*)(W + 18 * SB);
  u16* kT_l = (u16*)(W + 19 * SB);
  char* WB = W + 20 * SB;
  const size_t WS = 524288;
  u16* Wq_h = (u16*)(WB + 0 * WS);
  u16* Wk_h = (u16*)(WB + 1 * WS);
  u16* Wv_h = (u16*)(WB + 2 * WS);
  u16* Wfc_h = (u16*)(WB + 3 * WS);
  u16* Wqt_h = (u16*)(WB + 4 * WS);
  u16* Wqt_l = (u16*)(WB + 5 * WS);
  u16* Wkt_h = (u16*)(WB + 6 * WS);
  u16* Wkt_l = (u16*)(WB + 7 * WS);
  // aliases (lifetimes disjoint, stream-ordered)
  u16* qt_h = q_hi;
  u16* qt_l = q_lo;
  u16* kt_h = k_hi;
  u16* kt_l = k_lo;
  u16* vpT = v_hi;
  u16* attnB = dist_h;
  u16* out0 = qp_bf;
  float* out1 = qt0f;

  float* outO = (float*)d_out;
  float* attnF = outO + NLD;

  dim3 b256(256), b512(512);
  k_split<true><<<4096, b256, 0, stream>>>(q, q_hi, q_lo, NLD);
  k_split<true><<<4096, b256, 0, stream>>>(k, k_hi, k_lo, NLD);
  k_split<false><<<4096, b256, 0, stream>>>(v, v_hi, nullptr, NLD);
  k_split<true><<<4096, b256, 0, stream>>>(dist, dist_h, dist_l, NLL);
  k_split<false><<<256, b256, 0, stream>>>(Wq, Wq_h, nullptr, 262144);
  k_split<false><<<256, b256, 0, stream>>>(Wk, Wk_h, nullptr, 262144);
  k_split<false><<<256, b256, 0, stream>>>(Wv, Wv_h, nullptr, 262144);
  k_split<false><<<256, b256, 0, stream>>>(Wfc, Wfc_h, nullptr, 262144);
  k_split<true><<<256, b256, 0, stream>>>(Wqt, Wqt_h, Wqt_l, 262144);
  k_split<true><<<256, b256, 0, stream>>>(Wkt, Wkt_h, Wkt_l, 262144);

  k_proj_p<<<dim3(2, 64, 3), b512, 131072, stream>>>(
      q_hi, k_hi, v_hi, Wq_h, Wk_h, Wv_h, qp_bf, kp_bf, vp_bf);
  k_proj_t<<<dim3(2, 64, 2), b512, 131072, stream>>>(
      q_hi, q_lo, k_hi, k_lo, Wqt_h, Wqt_l, Wkt_h, Wkt_l, qt0f, kt0f);
  k_tsplit<<<dim3(8, 16, 32), b256, 0, stream>>>(qt0f, kt0f, qT_h, qT_l, kT_h,
                                                 kT_l);
  k_tbf16<<<dim3(8, 16, 16), b256, 0, stream>>>(vp_bf, vpT);
  k_dist_g<<<dim3(2, 4, 32), b512, 131072, stream>>>(
      dist_h, dist_l, qT_h, qT_l, kT_h, kT_l, qt_h, qt_l, kt_h, kt_l);
  k_score<<<dim3(4, 4, 16), b512, 131072, stream>>>(qp_bf, kp_bf, qt_h, qt_l,
                                                    kt_h, kt_l, lens, attnF,
                                                    attnB);
  k_pv<<<dim3(2, 8, 16), b512, 98304, stream>>>(attnB, vpT, out0);
  k_fc<<<dim3(2, 128, 1), b512, 98304, stream>>>(out0, Wfc_h, q, out1);
  k_ln<<<NB * LL, b256, 0, stream>>>(out1, gamma, beta, outO);
}

// Round 5
// 521.650 us; speedup vs baseline: 1.2056x; 1.1325x over previous
//
#include <hip/hip_runtime.h>
#include <math.h>

#define LL 1024
#define DD 512
#define NB 16

typedef __attribute__((ext_vector_type(8))) short bf16x8;
typedef __attribute__((ext_vector_type(4))) float f32x4;
typedef unsigned short u16;
typedef unsigned int u32;
typedef const __attribute__((address_space(1))) void* gptr_t;
typedef __attribute__((address_space(3))) void* sptr_t;

static const long NLD = (long)NB * LL * DD;  // 8,388,608
static const long NLL = (long)NB * LL * LL;  // 16,777,216

__device__ __forceinline__ u16 f2bf(float x) {
  u32 u = __float_as_uint(x);
  u += 0x7fffu + ((u >> 16) & 1u);
  return (u16)(u >> 16);
}
__device__ __forceinline__ float bf2f(u16 h) {
  return __uint_as_float((u32)h << 16);
}

// ---------------------------------------------------------------------------
// fp32 -> bf16 hi (+ optional lo residual) elementwise
// ---------------------------------------------------------------------------
template <bool SPLIT>
__global__ __launch_bounds__(256) void k_split(const float* __restrict__ x,
                                               u16* __restrict__ hi,
                                               u16* __restrict__ lo, long n) {
  const long stride = (long)gridDim.x * 1024;
  for (long i = ((long)blockIdx.x * 256 + threadIdx.x) * 4; i < n;
       i += stride) {
    const float4 v = *(const float4*)(x + i);
    ushort4 h;
    h.x = f2bf(v.x);
    h.y = f2bf(v.y);
    h.z = f2bf(v.z);
    h.w = f2bf(v.w);
    *(ushort4*)(hi + i) = h;
    if constexpr (SPLIT) {
      ushort4 s;
      s.x = f2bf(v.x - bf2f(h.x));
      s.y = f2bf(v.y - bf2f(h.y));
      s.z = f2bf(v.z - bf2f(h.z));
      s.w = f2bf(v.w - bf2f(h.w));
      *(ushort4*)(lo + i) = s;
    }
  }
}

// ---------------------------------------------------------------------------
// GEMM cores (round-2 proven structure): 256 threads = 4 waves (2x2), tile
// 128x128, BK=32, single-buffered LDS, 2 barriers/K-step. LDS rows = 64B;
// chunk-XOR swizzle cp = ks ^ ((r>>1)&3) on reads; staging keeps LDS dest
// LINEAR, inverse swizzle applied to per-lane GLOBAL source (0 conflicts
// measured). NISS = rows/64 (covers NISS*4KB).
// ---------------------------------------------------------------------------
template <int NISS>
__device__ __forceinline__ void stage_tile(const u16* __restrict__ G, long ld,
                                           int row0, int k0, char* lds, int w,
                                           int l) {
#pragma unroll
  for (int i = 0; i < NISS; ++i) {
    const int off = i * 4096 + w * 1024 + l * 16;
    const int r = off >> 6;
    const int cp = (off >> 4) & 3;
    const int c = cp ^ ((r >> 1) & 3);
    __builtin_amdgcn_global_load_lds(
        (gptr_t)(G + (long)(row0 + r) * ld + k0 + c * 8),
        (sptr_t)(lds + i * 4096 + w * 1024), 16, 0, 0);
  }
}

__device__ __forceinline__ bf16x8 read_frag(const char* lds, int r, int ks) {
  const int cp = ks ^ ((r >> 1) & 3);
  return *(const bf16x8*)(lds + r * 64 + cp * 16);
}

// plain bf16 NT: C += A(MxK,row-major) * B(NxK,row-major)^T
__device__ __forceinline__ void core_plain(const u16* __restrict__ A, long lda,
                                           const u16* __restrict__ B, long ldb,
                                           int K, int bm, int bn, char* smem,
                                           f32x4 acc[4][4]) {
  const int tid = threadIdx.x, w = tid >> 6, l = tid & 63;
  const int wm = (w >> 1) * 64, wn = (w & 1) * 64;
  const int fr = l & 15, ks = l >> 4;
  char* As = smem;
  char* Bs = smem + 8192;
  for (int k0 = 0; k0 < K; k0 += 32) {
    stage_tile<2>(A, lda, bm, k0, As, w, l);
    stage_tile<2>(B, ldb, bn, k0, Bs, w, l);
    __syncthreads();
    bf16x8 af[4], bg[4];
#pragma unroll
    for (int i = 0; i < 4; ++i) {
      af[i] = read_frag(As, wm + i * 16 + fr, ks);
      bg[i] = read_frag(Bs, wn + i * 16 + fr, ks);
    }
#pragma unroll
    for (int mi = 0; mi < 4; ++mi)
#pragma unroll
      for (int ni = 0; ni < 4; ++ni)
        acc[mi][ni] = __builtin_amdgcn_mfma_f32_16x16x32_bf16(
            af[mi], bg[ni], acc[mi][ni], 0, 0, 0);
    __syncthreads();
  }
}

// split bf16 NT: hh + hl + lh (3 MFMAs/pair). Load order hh -> bl -> al keeps
// peak live regs ~155 so 3 waves/SIMD (<=170 VGPR) fits without spills.
__device__ __forceinline__ void core_split(
    const u16* __restrict__ Ah, const u16* __restrict__ Al, long lda,
    const u16* __restrict__ Bh, const u16* __restrict__ Bl, long ldb, int K,
    int bm, int bn, char* smem, f32x4 acc[4][4]) {
  const int tid = threadIdx.x, w = tid >> 6, l = tid & 63;
  const int wm = (w >> 1) * 64, wn = (w & 1) * 64;
  const int fr = l & 15, ks = l >> 4;
  char* Ash = smem;
  char* Bsh = smem + 8192;
  char* Asl = smem + 16384;
  char* Bsl = smem + 24576;
  for (int k0 = 0; k0 < K; k0 += 32) {
    stage_tile<2>(Ah, lda, bm, k0, Ash, w, l);
    stage_tile<2>(Bh, ldb, bn, k0, Bsh, w, l);
    stage_tile<2>(Al, lda, bm, k0, Asl, w, l);
    stage_tile<2>(Bl, ldb, bn, k0, Bsl, w, l);
    __syncthreads();
    bf16x8 ah[4], bh[4];
#pragma unroll
    for (int i = 0; i < 4; ++i) {
      ah[i] = read_frag(Ash, wm + i * 16 + fr, ks);
      bh[i] = read_frag(Bsh, wn + i * 16 + fr, ks);
    }
#pragma unroll
    for (int mi = 0; mi < 4; ++mi)
#pragma unroll
      for (int ni = 0; ni < 4; ++ni)
        acc[mi][ni] = __builtin_amdgcn_mfma_f32_16x16x32_bf16(
            ah[mi], bh[ni], acc[mi][ni], 0, 0, 0);
    bf16x8 bl[4];
#pragma unroll
    for (int ni = 0; ni < 4; ++ni)
      bl[ni] = read_frag(Bsl, wn + ni * 16 + fr, ks);
#pragma unroll
    for (int mi = 0; mi < 4; ++mi)
#pragma unroll
      for (int ni = 0; ni < 4; ++ni)
        acc[mi][ni] = __builtin_amdgcn_mfma_f32_16x16x32_bf16(
            ah[mi], bl[ni], acc[mi][ni], 0, 0, 0);
    bf16x8 al[4];
#pragma unroll
    for (int mi = 0; mi < 4; ++mi)
      al[mi] = read_frag(Asl, wm + mi * 16 + fr, ks);
#pragma unroll
    for (int mi = 0; mi < 4; ++mi)
#pragma unroll
      for (int ni = 0; ni < 4; ++ni)
        acc[mi][ni] = __builtin_amdgcn_mfma_f32_16x16x32_bf16(
            al[mi], bh[ni], acc[mi][ni], 0, 0, 0);
    __syncthreads();
  }
}

// C/D coords: row = bm + wm + mi*16 + ks*4 + j, col = bn + wn + ni*16 + fr
#define EPI_PROLOG()                                       \
  const int tid = threadIdx.x, w = tid >> 6, l = tid & 63; \
  const int wm = (w >> 1) * 64, wn = (w & 1) * 64;         \
  const int fr = l & 15, ks = l >> 4;

// ---------------------------------------------------------------------------
// qp/kp/vp projections (plain bf16), bf16 output. grid (4, 128, 3)
// ---------------------------------------------------------------------------
__global__ __launch_bounds__(256, 3) void k_proj_p(
    const u16* __restrict__ q_hi, const u16* __restrict__ k_hi,
    const u16* __restrict__ v_hi, const u16* __restrict__ Wq_h,
    const u16* __restrict__ Wk_h, const u16* __restrict__ Wv_h,
    u16* __restrict__ qp, u16* __restrict__ kp, u16* __restrict__ vp) {
  const u16 *A, *B;
  u16* C;
  switch (blockIdx.z) {
    case 0: A = q_hi; B = Wq_h; C = qp; break;
    case 1: A = k_hi; B = Wk_h; C = kp; break;
    default: A = v_hi; B = Wv_h; C = vp; break;
  }
  __shared__ __align__(16) char smem[16384];
  const int bm = blockIdx.y * 128, bn = blockIdx.x * 128;
  f32x4 acc[4][4] = {};
  core_plain(A, DD, B, DD, DD, bm, bn, smem, acc);
  EPI_PROLOG()
#pragma unroll
  for (int mi = 0; mi < 4; ++mi) {
    const int R0 = bm + wm + mi * 16 + ks * 4;
#pragma unroll
    for (int ni = 0; ni < 4; ++ni) {
      const int col = bn + wn + ni * 16 + fr;
#pragma unroll
      for (int j = 0; j < 4; ++j)
        C[(long)(R0 + j) * DD + col] = f2bf(acc[mi][ni][j]);
    }
  }
}

// ---------------------------------------------------------------------------
// qt0/kt0 projections (split), SPLIT-bf16 output (no fp32 round trip).
// grid (4, 128, 2)
// ---------------------------------------------------------------------------
__global__ __launch_bounds__(256, 3) void k_proj_t(
    const u16* __restrict__ q_hi, const u16* __restrict__ q_lo,
    const u16* __restrict__ k_hi, const u16* __restrict__ k_lo,
    const u16* __restrict__ Wqt_h, const u16* __restrict__ Wqt_l,
    const u16* __restrict__ Wkt_h, const u16* __restrict__ Wkt_l,
    u16* __restrict__ qt0h, u16* __restrict__ qt0l, u16* __restrict__ kt0h,
    u16* __restrict__ kt0l) {
  const int sel = blockIdx.z;
  const u16* Ah = sel ? k_hi : q_hi;
  const u16* Al = sel ? k_lo : q_lo;
  const u16* Bh = sel ? Wkt_h : Wqt_h;
  const u16* Bl = sel ? Wkt_l : Wqt_l;
  u16* Ch = sel ? kt0h : qt0h;
  u16* Cl = sel ? kt0l : qt0l;
  __shared__ __align__(16) char smem[32768];
  const int bm = blockIdx.y * 128, bn = blockIdx.x * 128;
  f32x4 acc[4][4] = {};
  core_split(Ah, Al, DD, Bh, Bl, DD, DD, bm, bn, smem, acc);
  EPI_PROLOG()
#pragma unroll
  for (int mi = 0; mi < 4; ++mi) {
    const int R0 = bm + wm + mi * 16 + ks * 4;
#pragma unroll
    for (int ni = 0; ni < 4; ++ni) {
      const int col = bn + wn + ni * 16 + fr;
#pragma unroll
      for (int j = 0; j < 4; ++j) {
        const long idx = (long)(R0 + j) * DD + col;
        const float x = acc[mi][ni][j];
        const u16 h = f2bf(x);
        Ch[idx] = h;
        Cl[idx] = f2bf(x - bf2f(h));
      }
    }
  }
}

// ---------------------------------------------------------------------------
// generic per-batch bf16 transpose [1024][512] -> [512][1024]
// z = b*5 + s: s selects (qt0h,qt0l,kt0h,kt0l,vp) -> (qTh,qTl,kTh,kTl,vpT)
// grid (8, 16, 80)
// ---------------------------------------------------------------------------
__global__ __launch_bounds__(256) void k_tr(
    const u16* __restrict__ qt0h, const u16* __restrict__ qt0l,
    const u16* __restrict__ kt0h, const u16* __restrict__ kt0l,
    const u16* __restrict__ vp, u16* __restrict__ qTh, u16* __restrict__ qTl,
    u16* __restrict__ kTh, u16* __restrict__ kTl, u16* __restrict__ vpT) {
  const int z = blockIdx.z;
  const int b = z / 5, s = z - b * 5;
  const u16* X;
  u16* O;
  switch (s) {
    case 0: X = qt0h; O = qTh; break;
    case 1: X = qt0l; O = qTl; break;
    case 2: X = kt0h; O = kTh; break;
    case 3: X = kt0l; O = kTl; break;
    default: X = vp; O = vpT; break;
  }
  X += (long)b * LL * DD;
  O += (long)b * LL * DD;
  __shared__ u16 t[64][68];
  const int r0 = blockIdx.y * 64, c0 = blockIdx.x * 64;
  const int tid = threadIdx.x;
#pragma unroll
  for (int i = 0; i < 16; ++i) {
    const int idx = tid + i * 256;
    t[idx >> 6][idx & 63] = X[(long)(r0 + (idx >> 6)) * DD + c0 + (idx & 63)];
  }
  __syncthreads();
#pragma unroll
  for (int i = 0; i < 16; ++i) {
    const int idx = tid + i * 256;
    const int rr = idx >> 6, cc = idx & 63;
    O[(long)(c0 + rr) * LL + r0 + cc] = t[cc][rr];
  }
}

// ---------------------------------------------------------------------------
// distance matmuls (split): qt/kt = dist * {q,k}t0, split bf16 out.
// grid (4, 8, 32) with XCD-chunk swizzle (each XCD owns contiguous work).
// ---------------------------------------------------------------------------
__global__ __launch_bounds__(256, 3) void k_dist_g(
    const u16* __restrict__ dist_h, const u16* __restrict__ dist_l,
    const u16* __restrict__ qT_h, const u16* __restrict__ qT_l,
    const u16* __restrict__ kT_h, const u16* __restrict__ kT_l,
    u16* __restrict__ qt_h, u16* __restrict__ qt_l, u16* __restrict__ kt_h,
    u16* __restrict__ kt_l) {
  const int flat = blockIdx.x + (blockIdx.y << 2) + (blockIdx.z << 5);
  const int swz = ((flat & 7) << 7) | (flat >> 3);  // 1024 blocks, bijective
  const int bn = (swz & 3) << 7;
  const int bm = ((swz >> 2) & 7) << 7;
  const int zz = swz >> 5;
  const int b = zz >> 1, sel = zz & 1;
  const u16* Ah = dist_h + (long)b * LL * LL;
  const u16* Al = dist_l + (long)b * LL * LL;
  const u16* Bh = (sel ? kT_h : qT_h) + (long)b * LL * DD;
  const u16* Bl = (sel ? kT_l : qT_l) + (long)b * LL * DD;
  u16* Oh = (sel ? kt_h : qt_h) + (long)b * LL * DD;
  u16* Ol = (sel ? kt_l : qt_l) + (long)b * LL * DD;
  __shared__ __align__(16) char smem[32768];
  f32x4 acc[4][4] = {};
  core_split(Ah, Al, LL, Bh, Bl, LL, LL, bm, bn, smem, acc);
  EPI_PROLOG()
#pragma unroll
  for (int mi = 0; mi < 4; ++mi) {
    const int R0 = bm + wm + mi * 16 + ks * 4;
#pragma unroll
    for (int ni = 0; ni < 4; ++ni) {
      const int col = bn + wn + ni * 16 + fr;
#pragma unroll
      for (int j = 0; j < 4; ++j) {
        const long idx = (long)(R0 + j) * DD + col;
        const float x = acc[mi][ni][j];
        const u16 h = f2bf(x);
        Oh[idx] = h;
        Ol[idx] = f2bf(x - bf2f(h));
      }
    }
  }
}

// ---------------------------------------------------------------------------
// scores: split(qt,kt) + plain(qp,kp) -> mask+tanh -> attn fp32 + bf16
// grid (8, 8, 16) with XCD-chunk swizzle.
// ---------------------------------------------------------------------------
__global__ __launch_bounds__(256, 3) void k_score(
    const u16* __restrict__ qp, const u16* __restrict__ kp,
    const u16* __restrict__ qt_h, const u16* __restrict__ qt_l,
    const u16* __restrict__ kt_h, const u16* __restrict__ kt_l,
    const int* __restrict__ lens, float* __restrict__ attnF,
    u16* __restrict__ attnB) {
  const int flat = blockIdx.x + (blockIdx.y << 3) + (blockIdx.z << 6);
  const int swz = ((flat & 7) << 7) | (flat >> 3);  // 1024 blocks, bijective
  const int bn = (swz & 7) << 7;
  const int bm = ((swz >> 3) & 7) << 7;
  const int b = swz >> 6;
  const long od = (long)b * LL * DD;
  __shared__ __align__(16) char smem[32768];
  f32x4 acc[4][4] = {};
  core_split(qt_h + od, qt_l + od, DD, kt_h + od, kt_l + od, DD, DD, bm, bn,
             smem, acc);
  core_plain(qp + od, DD, kp + od, DD, DD, bm, bn, smem, acc);
  const int len = lens[b];
  const float invt = 0.04419417382415922f;  // 1/sqrt(512)
  EPI_PROLOG()
#pragma unroll
  for (int mi = 0; mi < 4; ++mi) {
    const int R0 = bm + wm + mi * 16 + ks * 4;
#pragma unroll
    for (int ni = 0; ni < 4; ++ni) {
      const int col = bn + wn + ni * 16 + fr;
      const float m = (col < len) ? 1.0f : 0.0f;
#pragma unroll
      for (int j = 0; j < 4; ++j) {
        const float s = tanhf(acc[mi][ni][j] * invt * m) * m;
        const long idx = (long)b * LL * LL + (long)(R0 + j) * LL + col;
        attnF[idx] = s;
        attnB[idx] = f2bf(s);
      }
    }
  }
}

// ---------------------------------------------------------------------------
// PV: out0 = attn * vp (plain, via vpT), bf16 out. grid (4, 8, 16)
// ---------------------------------------------------------------------------
__global__ __launch_bounds__(256, 3) void k_pv(const u16* __restrict__ attnB,
                                               const u16* __restrict__ vpT,
                                               u16* __restrict__ out0) {
  const int b = blockIdx.z;
  __shared__ __align__(16) char smem[16384];
  const int bm = blockIdx.y * 128, bn = blockIdx.x * 128;
  f32x4 acc[4][4] = {};
  core_plain(attnB + (long)b * LL * LL, LL, vpT + (long)b * LL * DD, LL, LL,
             bm, bn, smem, acc);
  u16* C = out0 + (long)b * LL * DD;
  EPI_PROLOG()
#pragma unroll
  for (int mi = 0; mi < 4; ++mi) {
    const int R0 = bm + wm + mi * 16 + ks * 4;
#pragma unroll
    for (int ni = 0; ni < 4; ++ni) {
      const int col = bn + wn + ni * 16 + fr;
#pragma unroll
      for (int j = 0; j < 4; ++j)
        C[(long)(R0 + j) * DD + col] = f2bf(acc[mi][ni][j]);
    }
  }
}

// ---------------------------------------------------------------------------
// Fused FC + residual + LayerNorm. Tile 64 rows x FULL 512 cols, 4 waves
// (1M x 4N: wave w owns cols [w*128, w*128+128)). After MFMA, add residual,
// row-reduce (shfl over 16 lanes + LDS over 4 waves), normalize, write outO.
// Kills out1 buffer and the separate LN pass. grid (256)
// ---------------------------------------------------------------------------
__global__ __launch_bounds__(256, 2) void k_fcln(
    const u16* __restrict__ out0, const u16* __restrict__ Wfc_h,
    const float* __restrict__ q, const float* __restrict__ gamma,
    const float* __restrict__ beta, float* __restrict__ outO) {
  __shared__ __align__(16) char smem[36864];  // As 4KB + Bs 32KB
  __shared__ float red[2][64][5];
  const int tid = threadIdx.x, w = tid >> 6, l = tid & 63;
  const int wn = w * 128;
  const int fr = l & 15, ks = l >> 4;
  const int bm = blockIdx.x * 64;
  char* As = smem;
  char* Bs = smem + 4096;
  f32x4 acc[4][8] = {};
  for (int k0 = 0; k0 < DD; k0 += 32) {
    stage_tile<1>(out0, DD, bm, k0, As, w, l);
    stage_tile<8>(Wfc_h, DD, 0, k0, Bs, w, l);
    __syncthreads();
    bf16x8 af[4], bg[8];
#pragma unroll
    for (int mi = 0; mi < 4; ++mi) af[mi] = read_frag(As, mi * 16 + fr, ks);
#pragma unroll
    for (int ni = 0; ni < 8; ++ni)
      bg[ni] = read_frag(Bs, wn + ni * 16 + fr, ks);
#pragma unroll
    for (int mi = 0; mi < 4; ++mi)
#pragma unroll
      for (int ni = 0; ni < 8; ++ni)
        acc[mi][ni] = __builtin_amdgcn_mfma_f32_16x16x32_bf16(
            af[mi], bg[ni], acc[mi][ni], 0, 0, 0);
    __syncthreads();
  }
  // residual add + per-row partial sums (rows: mi*16 + ks*4 + j)
  float p1[4][4], p2[4][4];
#pragma unroll
  for (int mi = 0; mi < 4; ++mi)
#pragma unroll
    for (int j = 0; j < 4; ++j) {
      p1[mi][j] = 0.0f;
      p2[mi][j] = 0.0f;
    }
#pragma unroll
  for (int mi = 0; mi < 4; ++mi) {
    const int r = mi * 16 + ks * 4;
#pragma unroll
    for (int ni = 0; ni < 8; ++ni) {
      const int col = wn + ni * 16 + fr;
#pragma unroll
      for (int j = 0; j < 4; ++j) {
        const float val =
            acc[mi][ni][j] + q[(long)(bm + r + j) * DD + col];
        acc[mi][ni][j] = val;
        p1[mi][j] += val;
        p2[mi][j] += val * val;
      }
    }
  }
#pragma unroll
  for (int off = 1; off < 16; off <<= 1) {
#pragma unroll
    for (int mi = 0; mi < 4; ++mi)
#pragma unroll
      for (int j = 0; j < 4; ++j) {
        p1[mi][j] += __shfl_xor(p1[mi][j], off);
        p2[mi][j] += __shfl_xor(p2[mi][j], off);
      }
  }
  if (fr == 0) {
#pragma unroll
    for (int mi = 0; mi < 4; ++mi)
#pragma unroll
      for (int j = 0; j < 4; ++j) {
        red[0][mi * 16 + ks * 4 + j][w] = p1[mi][j];
        red[1][mi * 16 + ks * 4 + j][w] = p2[mi][j];
      }
  }
  __syncthreads();
#pragma unroll
  for (int mi = 0; mi < 4; ++mi) {
#pragma unroll
    for (int j = 0; j < 4; ++j) {
      const int r = mi * 16 + ks * 4 + j;
      const float s1 = red[0][r][0] + red[0][r][1] + red[0][r][2] + red[0][r][3];
      const float s2 = red[1][r][0] + red[1][r][1] + red[1][r][2] + red[1][r][3];
      const float mu = s1 * (1.0f / DD);
      const float rs = rsqrtf(s2 * (1.0f / DD) - mu * mu + 1e-6f);
#pragma unroll
      for (int ni = 0; ni < 8; ++ni) {
        const int col = wn + ni * 16 + fr;
        outO[(long)(bm + r) * DD + col] =
            (acc[mi][ni][j] - mu) * rs * gamma[col] + beta[col];
      }
    }
  }
}

// ---------------------------------------------------------------------------
extern "C" void kernel_launch(void* const* d_in, const int* in_sizes, int n_in,
                              void* d_out, int out_size, void* d_ws,
                              size_t ws_size, hipStream_t stream) {
  const float* q = (const float*)d_in[0];
  const float* k = (const float*)d_in[1];
  const float* v = (const float*)d_in[2];
  const int* lens = (const int*)d_in[3];
  const float* dist = (const float*)d_in[4];
  const float* Wq = (const float*)d_in[5];
  const float* Wk = (const float*)d_in[6];
  const float* Wv = (const float*)d_in[7];
  const float* Wqt = (const float*)d_in[8];
  const float* Wkt = (const float*)d_in[9];
  const float* Wfc = (const float*)d_in[10];
  const float* gamma = (const float*)d_in[11];
  const float* beta = (const float*)d_in[12];

  char* W = (char*)d_ws;
  const size_t SB = 16777216;  // bytes of one bf16 [16384][512] buffer
  u16* q_hi = (u16*)(W + 0 * SB);    // reused later as qt_h
  u16* q_lo = (u16*)(W + 1 * SB);    // reused later as qt_l
  u16* k_hi = (u16*)(W + 2 * SB);    // reused later as kt_h
  u16* k_lo = (u16*)(W + 3 * SB);    // reused later as kt_l
  u16* v_hi = (u16*)(W + 4 * SB);    // reused later as vpT
  u16* dist_h = (u16*)(W + 5 * SB);  // 2SB; reused later as attnB
  u16* dist_l = (u16*)(W + 7 * SB);  // 2SB
  u16* qp_bf = (u16*)(W + 9 * SB);   // reused later as out0
  u16* kp_bf = (u16*)(W + 10 * SB);
  u16* vp_bf = (u16*)(W + 11 * SB);
  u16* qt0h = (u16*)(W + 12 * SB);
  u16* qt0l = (u16*)(W + 13 * SB);
  u16* kt0h = (u16*)(W + 14 * SB);
  u16* kt0l = (u16*)(W + 15 * SB);
  u16* qT_h = (u16*)(W + 16 * SB);
  u16* qT_l = (u16*)(W + 17 * SB);
  u16* kT_h = (u16*)(W + 18 * SB);
  u16* kT_l = (u16*)(W + 19 * SB);
  char* WB = W + 20 * SB;
  const size_t WS = 524288;
  u16* Wq_h = (u16*)(WB + 0 * WS);
  u16* Wk_h = (u16*)(WB + 1 * WS);
  u16* Wv_h = (u16*)(WB + 2 * WS);
  u16* Wfc_h = (u16*)(WB + 3 * WS);
  u16* Wqt_h = (u16*)(WB + 4 * WS);
  u16* Wqt_l = (u16*)(WB + 5 * WS);
  u16* Wkt_h = (u16*)(WB + 6 * WS);
  u16* Wkt_l = (u16*)(WB + 7 * WS);
  // aliases (lifetimes disjoint, stream-ordered)
  u16* qt_h = q_hi;
  u16* qt_l = q_lo;
  u16* kt_h = k_hi;
  u16* kt_l = k_lo;
  u16* vpT = v_hi;
  u16* attnB = dist_h;
  u16* out0 = qp_bf;

  float* outO = (float*)d_out;
  float* attnF = outO + NLD;

  dim3 blk(256);
  k_split<true><<<4096, blk, 0, stream>>>(q, q_hi, q_lo, NLD);
  k_split<true><<<4096, blk, 0, stream>>>(k, k_hi, k_lo, NLD);
  k_split<false><<<4096, blk, 0, stream>>>(v, v_hi, nullptr, NLD);
  k_split<true><<<4096, blk, 0, stream>>>(dist, dist_h, dist_l, NLL);
  k_split<false><<<256, blk, 0, stream>>>(Wq, Wq_h, nullptr, 262144);
  k_split<false><<<256, blk, 0, stream>>>(Wk, Wk_h, nullptr, 262144);
  k_split<false><<<256, blk, 0, stream>>>(Wv, Wv_h, nullptr, 262144);
  k_split<false><<<256, blk, 0, stream>>>(Wfc, Wfc_h, nullptr, 262144);
  k_split<true><<<256, blk, 0, stream>>>(Wqt, Wqt_h, Wqt_l, 262144);
  k_split<true><<<256, blk, 0, stream>>>(Wkt, Wkt_h, Wkt_l, 262144);

  k_proj_p<<<dim3(4, 128, 3), blk, 0, stream>>>(q_hi, k_hi, v_hi, Wq_h, Wk_h,
                                                Wv_h, qp_bf, kp_bf, vp_bf);
  k_proj_t<<<dim3(4, 128, 2), blk, 0, stream>>>(q_hi, q_lo, k_hi, k_lo, Wqt_h,
                                                Wqt_l, Wkt_h, Wkt_l, qt0h,
                                                qt0l, kt0h, kt0l);
  k_tr<<<dim3(8, 16, 80), blk, 0, stream>>>(qt0h, qt0l, kt0h, kt0l, vp_bf,
                                            qT_h, qT_l, kT_h, kT_l, vpT);
  k_dist_g<<<dim3(4, 8, 32), blk, 0, stream>>>(dist_h, dist_l, qT_h, qT_l,
                                               kT_h, kT_l, qt_h, qt_l, kt_h,
                                               kt_l);
  k_score<<<dim3(8, 8, 16), blk, 0, stream>>>(qp_bf, kp_bf, qt_h, qt_l, kt_h,
                                              kt_l, lens, attnF, attnB);
  k_pv<<<dim3(4, 8, 16), blk, 0, stream>>>(attnB, vpT, out0);
  k_fcln<<<dim3(256), blk, 0, stream>>>(out0, Wfc_h, q, gamma, beta, outO);
}

// Round 6
// 453.901 us; speedup vs baseline: 1.3856x; 1.1493x over previous
//
#include <hip/hip_runtime.h>
#include <math.h>

#define LL 1024
#define DD 512
#define NB 16

typedef __attribute__((ext_vector_type(8))) short bf16x8;
typedef __attribute__((ext_vector_type(4))) float f32x4;
typedef unsigned short u16;
typedef unsigned int u32;
typedef const __attribute__((address_space(1))) void* gptr_t;
typedef __attribute__((address_space(3))) void* sptr_t;

static const long NLD = (long)NB * LL * DD;  // 8,388,608
static const long NLL = (long)NB * LL * LL;  // 16,777,216

__device__ __forceinline__ u16 f2bf(float x) {
  u32 u = __float_as_uint(x);
  u += 0x7fffu + ((u >> 16) & 1u);
  return (u16)(u >> 16);
}
__device__ __forceinline__ float bf2f(u16 h) {
  return __uint_as_float((u32)h << 16);
}

// ---------------------------------------------------------------------------
// q/k/v -> bf16 hi(+lo) in one launch. z: 0=q(split) 1=k(split) 2=v(plain)
// ---------------------------------------------------------------------------
__global__ __launch_bounds__(256) void k_split3(
    const float* __restrict__ q, const float* __restrict__ k,
    const float* __restrict__ v, u16* __restrict__ qh, u16* __restrict__ ql,
    u16* __restrict__ kh, u16* __restrict__ kl, u16* __restrict__ vh) {
  const int z = blockIdx.z;
  const float* x = (z == 0) ? q : (z == 1) ? k : v;
  u16* hi = (z == 0) ? qh : (z == 1) ? kh : vh;
  u16* lo = (z == 0) ? ql : kl;
  const long stride = (long)gridDim.x * 1024;
  for (long i = ((long)blockIdx.x * 256 + threadIdx.x) * 4; i < NLD;
       i += stride) {
    const float4 vv = *(const float4*)(x + i);
    ushort4 h;
    h.x = f2bf(vv.x);
    h.y = f2bf(vv.y);
    h.z = f2bf(vv.z);
    h.w = f2bf(vv.w);
    *(ushort4*)(hi + i) = h;
    if (z < 2) {
      ushort4 s;
      s.x = f2bf(vv.x - bf2f(h.x));
      s.y = f2bf(vv.y - bf2f(h.y));
      s.z = f2bf(vv.z - bf2f(h.z));
      s.w = f2bf(vv.w - bf2f(h.w));
      *(ushort4*)(lo + i) = s;
    }
  }
}

// dist -> split bf16 (big, own launch)
__global__ __launch_bounds__(256) void k_splitd(const float* __restrict__ x,
                                                u16* __restrict__ hi,
                                                u16* __restrict__ lo) {
  const long stride = (long)gridDim.x * 1024;
  for (long i = ((long)blockIdx.x * 256 + threadIdx.x) * 4; i < NLL;
       i += stride) {
    const float4 v = *(const float4*)(x + i);
    ushort4 h, s;
    h.x = f2bf(v.x);
    h.y = f2bf(v.y);
    h.z = f2bf(v.z);
    h.w = f2bf(v.w);
    s.x = f2bf(v.x - bf2f(h.x));
    s.y = f2bf(v.y - bf2f(h.y));
    s.z = f2bf(v.z - bf2f(h.z));
    s.w = f2bf(v.w - bf2f(h.w));
    *(ushort4*)(hi + i) = h;
    *(ushort4*)(lo + i) = s;
  }
}

// all 6 weights in one launch. z: 0..3 plain (Wq,Wk,Wv,Wfc), 4..5 split
// (Wqt,Wkt). 256 blocks x 256 thr x 4 = 262144 elements exactly.
__global__ __launch_bounds__(256) void k_splitw(
    const float* __restrict__ Wq, const float* __restrict__ Wk,
    const float* __restrict__ Wv, const float* __restrict__ Wfc,
    const float* __restrict__ Wqt, const float* __restrict__ Wkt,
    u16* __restrict__ Wq_h, u16* __restrict__ Wk_h, u16* __restrict__ Wv_h,
    u16* __restrict__ Wfc_h, u16* __restrict__ Wqt_h,
    u16* __restrict__ Wqt_l, u16* __restrict__ Wkt_h,
    u16* __restrict__ Wkt_l) {
  const int z = blockIdx.z;
  const float* x;
  u16 *hi, *lo = nullptr;
  switch (z) {
    case 0: x = Wq; hi = Wq_h; break;
    case 1: x = Wk; hi = Wk_h; break;
    case 2: x = Wv; hi = Wv_h; break;
    case 3: x = Wfc; hi = Wfc_h; break;
    case 4: x = Wqt; hi = Wqt_h; lo = Wqt_l; break;
    default: x = Wkt; hi = Wkt_h; lo = Wkt_l; break;
  }
  const long i = ((long)blockIdx.x * 256 + threadIdx.x) * 4;
  const float4 v = *(const float4*)(x + i);
  ushort4 h;
  h.x = f2bf(v.x);
  h.y = f2bf(v.y);
  h.z = f2bf(v.z);
  h.w = f2bf(v.w);
  *(ushort4*)(hi + i) = h;
  if (z >= 4) {
    ushort4 s;
    s.x = f2bf(v.x - bf2f(h.x));
    s.y = f2bf(v.y - bf2f(h.y));
    s.z = f2bf(v.z - bf2f(h.z));
    s.w = f2bf(v.w - bf2f(h.w));
    *(ushort4*)(lo + i) = s;
  }
}

// ---------------------------------------------------------------------------
// GEMM cores (round-2/5 proven): 256 threads = 4 waves (2x2), tile 128x128,
// BK=32, single-buffered LDS, 2 barriers/K-step. LDS rows 64B; chunk-XOR
// swizzle cp = ks ^ ((r>>1)&3) on reads; staging keeps LDS dest LINEAR with
// inverse swizzle on the per-lane GLOBAL source (0 conflicts measured).
// ---------------------------------------------------------------------------
template <int NISS>
__device__ __forceinline__ void stage_tile(const u16* __restrict__ G, long ld,
                                           int row0, int k0, char* lds, int w,
                                           int l) {
#pragma unroll
  for (int i = 0; i < NISS; ++i) {
    const int off = i * 4096 + w * 1024 + l * 16;
    const int r = off >> 6;
    const int cp = (off >> 4) & 3;
    const int c = cp ^ ((r >> 1) & 3);
    __builtin_amdgcn_global_load_lds(
        (gptr_t)(G + (long)(row0 + r) * ld + k0 + c * 8),
        (sptr_t)(lds + i * 4096 + w * 1024), 16, 0, 0);
  }
}

__device__ __forceinline__ bf16x8 read_frag(const char* lds, int r, int ks) {
  const int cp = ks ^ ((r >> 1) & 3);
  return *(const bf16x8*)(lds + r * 64 + cp * 16);
}

__device__ __forceinline__ void core_plain(const u16* __restrict__ A, long lda,
                                           const u16* __restrict__ B, long ldb,
                                           int K, int bm, int bn, char* smem,
                                           f32x4 acc[4][4]) {
  const int tid = threadIdx.x, w = tid >> 6, l = tid & 63;
  const int wm = (w >> 1) * 64, wn = (w & 1) * 64;
  const int fr = l & 15, ks = l >> 4;
  char* As = smem;
  char* Bs = smem + 8192;
  for (int k0 = 0; k0 < K; k0 += 32) {
    stage_tile<2>(A, lda, bm, k0, As, w, l);
    stage_tile<2>(B, ldb, bn, k0, Bs, w, l);
    __syncthreads();
    bf16x8 af[4], bg[4];
#pragma unroll
    for (int i = 0; i < 4; ++i) {
      af[i] = read_frag(As, wm + i * 16 + fr, ks);
      bg[i] = read_frag(Bs, wn + i * 16 + fr, ks);
    }
#pragma unroll
    for (int mi = 0; mi < 4; ++mi)
#pragma unroll
      for (int ni = 0; ni < 4; ++ni)
        acc[mi][ni] = __builtin_amdgcn_mfma_f32_16x16x32_bf16(
            af[mi], bg[ni], acc[mi][ni], 0, 0, 0);
    __syncthreads();
  }
}

// split bf16 NT: hh + hl + lh (3 MFMAs/pair)
__device__ __forceinline__ void core_split(
    const u16* __restrict__ Ah, const u16* __restrict__ Al, long lda,
    const u16* __restrict__ Bh, const u16* __restrict__ Bl, long ldb, int K,
    int bm, int bn, char* smem, f32x4 acc[4][4]) {
  const int tid = threadIdx.x, w = tid >> 6, l = tid & 63;
  const int wm = (w >> 1) * 64, wn = (w & 1) * 64;
  const int fr = l & 15, ks = l >> 4;
  char* Ash = smem;
  char* Bsh = smem + 8192;
  char* Asl = smem + 16384;
  char* Bsl = smem + 24576;
  for (int k0 = 0; k0 < K; k0 += 32) {
    stage_tile<2>(Ah, lda, bm, k0, Ash, w, l);
    stage_tile<2>(Bh, ldb, bn, k0, Bsh, w, l);
    stage_tile<2>(Al, lda, bm, k0, Asl, w, l);
    stage_tile<2>(Bl, ldb, bn, k0, Bsl, w, l);
    __syncthreads();
    bf16x8 ah[4], bh[4];
#pragma unroll
    for (int i = 0; i < 4; ++i) {
      ah[i] = read_frag(Ash, wm + i * 16 + fr, ks);
      bh[i] = read_frag(Bsh, wn + i * 16 + fr, ks);
    }
#pragma unroll
    for (int mi = 0; mi < 4; ++mi)
#pragma unroll
      for (int ni = 0; ni < 4; ++ni)
        acc[mi][ni] = __builtin_amdgcn_mfma_f32_16x16x32_bf16(
            ah[mi], bh[ni], acc[mi][ni], 0, 0, 0);
    bf16x8 bl[4];
#pragma unroll
    for (int ni = 0; ni < 4; ++ni)
      bl[ni] = read_frag(Bsl, wn + ni * 16 + fr, ks);
#pragma unroll
    for (int mi = 0; mi < 4; ++mi)
#pragma unroll
      for (int ni = 0; ni < 4; ++ni)
        acc[mi][ni] = __builtin_amdgcn_mfma_f32_16x16x32_bf16(
            ah[mi], bl[ni], acc[mi][ni], 0, 0, 0);
    bf16x8 al[4];
#pragma unroll
    for (int mi = 0; mi < 4; ++mi)
      al[mi] = read_frag(Asl, wm + mi * 16 + fr, ks);
#pragma unroll
    for (int mi = 0; mi < 4; ++mi)
#pragma unroll
      for (int ni = 0; ni < 4; ++ni)
        acc[mi][ni] = __builtin_amdgcn_mfma_f32_16x16x32_bf16(
            al[mi], bh[ni], acc[mi][ni], 0, 0, 0);
    __syncthreads();
  }
}

// C/D coords: row = bm + wm + mi*16 + ks*4 + j, col = bn + wn + ni*16 + fr
#define EPI_PROLOG()                                       \
  const int tid = threadIdx.x, w = tid >> 6, l = tid & 63; \
  const int wm = (w >> 1) * 64, wn = (w & 1) * 64;         \
  const int fr = l & 15, ks = l >> 4;

// ---------------------------------------------------------------------------
// qp/kp/vp projections. kp (z=1) and vp (z=2) rows >= len feed only
// masked-out attn columns / zero-weighted PV terms -> skip those row-blocks.
// grid (4, 128, 3)
// ---------------------------------------------------------------------------
__global__ __launch_bounds__(256, 3) void k_proj_p(
    const u16* __restrict__ q_hi, const u16* __restrict__ k_hi,
    const u16* __restrict__ v_hi, const u16* __restrict__ Wq_h,
    const u16* __restrict__ Wk_h, const u16* __restrict__ Wv_h,
    const int* __restrict__ lens, u16* __restrict__ qp, u16* __restrict__ kp,
    u16* __restrict__ vp) {
  const int bm = blockIdx.y * 128, bn = blockIdx.x * 128;
  const u16 *A, *B;
  u16* C;
  switch (blockIdx.z) {
    case 0: A = q_hi; B = Wq_h; C = qp; break;
    case 1: A = k_hi; B = Wk_h; C = kp; break;
    default: A = v_hi; B = Wv_h; C = vp; break;
  }
  if (blockIdx.z != 0) {
    const int len = lens[bm >> 10];
    if ((bm & 1023) >= len) return;  // dead rows (masked/zero-weighted)
  }
  __shared__ __align__(16) char smem[16384];
  f32x4 acc[4][4] = {};
  core_plain(A, DD, B, DD, DD, bm, bn, smem, acc);
  EPI_PROLOG()
#pragma unroll
  for (int mi = 0; mi < 4; ++mi) {
    const int R0 = bm + wm + mi * 16 + ks * 4;
#pragma unroll
    for (int ni = 0; ni < 4; ++ni) {
      const int col = bn + wn + ni * 16 + fr;
#pragma unroll
      for (int j = 0; j < 4; ++j)
        C[(long)(R0 + j) * DD + col] = f2bf(acc[mi][ni][j]);
    }
  }
}

// ---------------------------------------------------------------------------
// qt0/kt0 projections (split), split-bf16 output. grid (4, 128, 2)
// ---------------------------------------------------------------------------
__global__ __launch_bounds__(256, 3) void k_proj_t(
    const u16* __restrict__ q_hi, const u16* __restrict__ q_lo,
    const u16* __restrict__ k_hi, const u16* __restrict__ k_lo,
    const u16* __restrict__ Wqt_h, const u16* __restrict__ Wqt_l,
    const u16* __restrict__ Wkt_h, const u16* __restrict__ Wkt_l,
    u16* __restrict__ qt0h, u16* __restrict__ qt0l, u16* __restrict__ kt0h,
    u16* __restrict__ kt0l) {
  const int sel = blockIdx.z;
  const u16* Ah = sel ? k_hi : q_hi;
  const u16* Al = sel ? k_lo : q_lo;
  const u16* Bh = sel ? Wkt_h : Wqt_h;
  const u16* Bl = sel ? Wkt_l : Wqt_l;
  u16* Ch = sel ? kt0h : qt0h;
  u16* Cl = sel ? kt0l : qt0l;
  __shared__ __align__(16) char smem[32768];
  const int bm = blockIdx.y * 128, bn = blockIdx.x * 128;
  f32x4 acc[4][4] = {};
  core_split(Ah, Al, DD, Bh, Bl, DD, DD, bm, bn, smem, acc);
  EPI_PROLOG()
#pragma unroll
  for (int mi = 0; mi < 4; ++mi) {
    const int R0 = bm + wm + mi * 16 + ks * 4;
#pragma unroll
    for (int ni = 0; ni < 4; ++ni) {
      const int col = bn + wn + ni * 16 + fr;
#pragma unroll
      for (int j = 0; j < 4; ++j) {
        const long idx = (long)(R0 + j) * DD + col;
        const float x = acc[mi][ni][j];
        const u16 h = f2bf(x);
        Ch[idx] = h;
        Cl[idx] = f2bf(x - bf2f(h));
      }
    }
  }
}

// ---------------------------------------------------------------------------
// per-batch bf16 transpose [1024][512] -> [512][1024]
// z = b*5 + s: (qt0h,qt0l,kt0h,kt0l,vp) -> (qTh,qTl,kTh,kTl,vpT)
// vp slabs with source rows >= len are only ever zero-weighted -> skip.
// grid (8, 16, 80)
// ---------------------------------------------------------------------------
__global__ __launch_bounds__(256) void k_tr(
    const u16* __restrict__ qt0h, const u16* __restrict__ qt0l,
    const u16* __restrict__ kt0h, const u16* __restrict__ kt0l,
    const u16* __restrict__ vp, const int* __restrict__ lens,
    u16* __restrict__ qTh, u16* __restrict__ qTl, u16* __restrict__ kTh,
    u16* __restrict__ kTl, u16* __restrict__ vpT) {
  const int z = blockIdx.z;
  const int b = z / 5, s = z - b * 5;
  const int r0 = blockIdx.y * 64, c0 = blockIdx.x * 64;
  if (s == 4 && r0 >= lens[b]) return;
  const u16* X;
  u16* O;
  switch (s) {
    case 0: X = qt0h; O = qTh; break;
    case 1: X = qt0l; O = qTl; break;
    case 2: X = kt0h; O = kTh; break;
    case 3: X = kt0l; O = kTl; break;
    default: X = vp; O = vpT; break;
  }
  X += (long)b * LL * DD;
  O += (long)b * LL * DD;
  __shared__ u16 t[64][68];
  const int tid = threadIdx.x;
#pragma unroll
  for (int i = 0; i < 16; ++i) {
    const int idx = tid + i * 256;
    t[idx >> 6][idx & 63] = X[(long)(r0 + (idx >> 6)) * DD + c0 + (idx & 63)];
  }
  __syncthreads();
#pragma unroll
  for (int i = 0; i < 16; ++i) {
    const int idx = tid + i * 256;
    const int rr = idx >> 6, cc = idx & 63;
    O[(long)(c0 + rr) * LL + r0 + cc] = t[cc][rr];
  }
}

// ---------------------------------------------------------------------------
// distance matmuls (split): qt/kt = dist * {q,k}t0. kt rows >= len feed only
// masked attn columns -> skip those blocks (sel==1).
// grid (4, 8, 32), XCD-chunk swizzle.
// ---------------------------------------------------------------------------
__global__ __launch_bounds__(256, 3) void k_dist_g(
    const u16* __restrict__ dist_h, const u16* __restrict__ dist_l,
    const u16* __restrict__ qT_h, const u16* __restrict__ qT_l,
    const u16* __restrict__ kT_h, const u16* __restrict__ kT_l,
    const int* __restrict__ lens, u16* __restrict__ qt_h,
    u16* __restrict__ qt_l, u16* __restrict__ kt_h, u16* __restrict__ kt_l) {
  const int flat = blockIdx.x + (blockIdx.y << 2) + (blockIdx.z << 5);
  const int swz = ((flat & 7) << 7) | (flat >> 3);  // 1024 blocks, bijective
  const int bn = (swz & 3) << 7;
  const int bm = ((swz >> 2) & 7) << 7;
  const int zz = swz >> 5;
  const int b = zz >> 1, sel = zz & 1;
  if (sel == 1 && bm >= lens[b]) return;  // dead kt rows
  const u16* Ah = dist_h + (long)b * LL * LL;
  const u16* Al = dist_l + (long)b * LL * LL;
  const u16* Bh = (sel ? kT_h : qT_h) + (long)b * LL * DD;
  const u16* Bl = (sel ? kT_l : qT_l) + (long)b * LL * DD;
  u16* Oh = (sel ? kt_h : qt_h) + (long)b * LL * DD;
  u16* Ol = (sel ? kt_l : qt_l) + (long)b * LL * DD;
  __shared__ __align__(16) char smem[32768];
  f32x4 acc[4][4] = {};
  core_split(Ah, Al, LL, Bh, Bl, LL, LL, bm, bn, smem, acc);
  EPI_PROLOG()
#pragma unroll
  for (int mi = 0; mi < 4; ++mi) {
    const int R0 = bm + wm + mi * 16 + ks * 4;
#pragma unroll
    for (int ni = 0; ni < 4; ++ni) {
      const int col = bn + wn + ni * 16 + fr;
#pragma unroll
      for (int j = 0; j < 4; ++j) {
        const long idx = (long)(R0 + j) * DD + col;
        const float x = acc[mi][ni][j];
        const u16 h = f2bf(x);
        Oh[idx] = h;
        Ol[idx] = f2bf(x - bf2f(h));
      }
    }
  }
}

// ---------------------------------------------------------------------------
// scores, single merged K-loop: split(qt,kt) + plain(qp,kp) staged together
// (6 LDS tiles, 48KB; 64 MFMA per barrier pair). Blocks with bn >= len write
// exact zeros and skip all compute. grid (8, 8, 16), XCD-chunk swizzle.
// ---------------------------------------------------------------------------
__global__ __launch_bounds__(256, 3) void k_score(
    const u16* __restrict__ qp, const u16* __restrict__ kp,
    const u16* __restrict__ qt_h, const u16* __restrict__ qt_l,
    const u16* __restrict__ kt_h, const u16* __restrict__ kt_l,
    const int* __restrict__ lens, float* __restrict__ attnF,
    u16* __restrict__ attnB) {
  const int flat = blockIdx.x + (blockIdx.y << 3) + (blockIdx.z << 6);
  const int swz = ((flat & 7) << 7) | (flat >> 3);  // 1024 blocks, bijective
  const int bn = (swz & 7) << 7;
  const int bm = ((swz >> 3) & 7) << 7;
  const int b = swz >> 6;
  const int len = lens[b];
  const int tid = threadIdx.x;
  const long baseF = (long)b * LL * LL;
  if (bn >= len) {  // fully-masked tile: output is exactly zero
    const float4 zf = make_float4(0.f, 0.f, 0.f, 0.f);
    const ushort4 zh = {0, 0, 0, 0};
    for (int i = tid; i < 4096; i += 256) {
      const int row = i >> 5, c = (i & 31) << 2;
      const long idx = baseF + (long)(bm + row) * LL + bn + c;
      *(float4*)&attnF[idx] = zf;
      *(ushort4*)&attnB[idx] = zh;
    }
    return;
  }
  const long od = (long)b * LL * DD;
  const u16* Ah = qt_h + od;
  const u16* Al = qt_l + od;
  const u16* Bh = kt_h + od;
  const u16* Bl = kt_l + od;
  const u16* Ap = qp + od;
  const u16* Bp = kp + od;
  __shared__ __align__(16) char smem[49152];
  char* Ash = smem;
  char* Bsh = smem + 8192;
  char* Asl = smem + 16384;
  char* Bsl = smem + 24576;
  char* Aps = smem + 32768;
  char* Bps = smem + 40960;
  const int w = tid >> 6, l = tid & 63;
  const int wm = (w >> 1) * 64, wn = (w & 1) * 64;
  const int fr = l & 15, ks = l >> 4;
  f32x4 acc[4][4] = {};
  for (int k0 = 0; k0 < DD; k0 += 32) {
    stage_tile<2>(Ah, DD, bm, k0, Ash, w, l);
    stage_tile<2>(Bh, DD, bn, k0, Bsh, w, l);
    stage_tile<2>(Al, DD, bm, k0, Asl, w, l);
    stage_tile<2>(Bl, DD, bn, k0, Bsl, w, l);
    stage_tile<2>(Ap, DD, bm, k0, Aps, w, l);
    stage_tile<2>(Bp, DD, bn, k0, Bps, w, l);
    __syncthreads();
    bf16x8 ah[4], bh[4];
#pragma unroll
    for (int i = 0; i < 4; ++i) {
      ah[i] = read_frag(Ash, wm + i * 16 + fr, ks);
      bh[i] = read_frag(Bsh, wn + i * 16 + fr, ks);
    }
#pragma unroll
    for (int mi = 0; mi < 4; ++mi)
#pragma unroll
      for (int ni = 0; ni < 4; ++ni)
        acc[mi][ni] = __builtin_amdgcn_mfma_f32_16x16x32_bf16(
            ah[mi], bh[ni], acc[mi][ni], 0, 0, 0);
    bf16x8 bl[4];
#pragma unroll
    for (int ni = 0; ni < 4; ++ni)
      bl[ni] = read_frag(Bsl, wn + ni * 16 + fr, ks);
#pragma unroll
    for (int mi = 0; mi < 4; ++mi)
#pragma unroll
      for (int ni = 0; ni < 4; ++ni)
        acc[mi][ni] = __builtin_amdgcn_mfma_f32_16x16x32_bf16(
            ah[mi], bl[ni], acc[mi][ni], 0, 0, 0);
    bf16x8 al[4];
#pragma unroll
    for (int mi = 0; mi < 4; ++mi)
      al[mi] = read_frag(Asl, wm + mi * 16 + fr, ks);
#pragma unroll
    for (int mi = 0; mi < 4; ++mi)
#pragma unroll
      for (int ni = 0; ni < 4; ++ni)
        acc[mi][ni] = __builtin_amdgcn_mfma_f32_16x16x32_bf16(
            al[mi], bh[ni], acc[mi][ni], 0, 0, 0);
    bf16x8 ap[4], bp[4];
#pragma unroll
    for (int i = 0; i < 4; ++i) {
      ap[i] = read_frag(Aps, wm + i * 16 + fr, ks);
      bp[i] = read_frag(Bps, wn + i * 16 + fr, ks);
    }
#pragma unroll
    for (int mi = 0; mi < 4; ++mi)
#pragma unroll
      for (int ni = 0; ni < 4; ++ni)
        acc[mi][ni] = __builtin_amdgcn_mfma_f32_16x16x32_bf16(
            ap[mi], bp[ni], acc[mi][ni], 0, 0, 0);
    __syncthreads();
  }
  const float invt = 0.04419417382415922f;  // 1/sqrt(512)
#pragma unroll
  for (int mi = 0; mi < 4; ++mi) {
    const int R0 = bm + wm + mi * 16 + ks * 4;
#pragma unroll
    for (int ni = 0; ni < 4; ++ni) {
      const int col = bn + wn + ni * 16 + fr;
      const float m = (col < len) ? 1.0f : 0.0f;
#pragma unroll
      for (int j = 0; j < 4; ++j) {
        const float s = tanhf(acc[mi][ni][j] * invt * m) * m;
        const long idx = baseF + (long)(R0 + j) * LL + col;
        attnF[idx] = s;
        attnB[idx] = f2bf(s);
      }
    }
  }
}

// ---------------------------------------------------------------------------
// PV: out0 = attn * vp (via vpT). attnB cols >= len are exact zeros -> K-loop
// truncated to ceil(len/32)*32. grid (4, 8, 16)
// ---------------------------------------------------------------------------
__global__ __launch_bounds__(256, 3) void k_pv(const u16* __restrict__ attnB,
                                               const u16* __restrict__ vpT,
                                               const int* __restrict__ lens,
                                               u16* __restrict__ out0) {
  const int b = blockIdx.z;
  const int Kt = ((lens[b] + 31) >> 5) << 5;
  __shared__ __align__(16) char smem[16384];
  const int bm = blockIdx.y * 128, bn = blockIdx.x * 128;
  f32x4 acc[4][4] = {};
  core_plain(attnB + (long)b * LL * LL, LL, vpT + (long)b * LL * DD, LL, Kt,
             bm, bn, smem, acc);
  u16* C = out0 + (long)b * LL * DD;
  EPI_PROLOG()
#pragma unroll
  for (int mi = 0; mi < 4; ++mi) {
    const int R0 = bm + wm + mi * 16 + ks * 4;
#pragma unroll
    for (int ni = 0; ni < 4; ++ni) {
      const int col = bn + wn + ni * 16 + fr;
#pragma unroll
      for (int j = 0; j < 4; ++j)
        C[(long)(R0 + j) * DD + col] = f2bf(acc[mi][ni][j]);
    }
  }
}

// ---------------------------------------------------------------------------
// Fused FC + residual + LayerNorm. 64 rows x full 512 cols per block.
// grid (256)
// ---------------------------------------------------------------------------
__global__ __launch_bounds__(256, 2) void k_fcln(
    const u16* __restrict__ out0, const u16* __restrict__ Wfc_h,
    const float* __restrict__ q, const float* __restrict__ gamma,
    const float* __restrict__ beta, float* __restrict__ outO) {
  __shared__ __align__(16) char smem[36864];  // As 4KB + Bs 32KB
  __shared__ float red[2][64][5];
  const int tid = threadIdx.x, w = tid >> 6, l = tid & 63;
  const int wn = w * 128;
  const int fr = l & 15, ks = l >> 4;
  const int bm = blockIdx.x * 64;
  char* As = smem;
  char* Bs = smem + 4096;
  f32x4 acc[4][8] = {};
  for (int k0 = 0; k0 < DD; k0 += 32) {
    stage_tile<1>(out0, DD, bm, k0, As, w, l);
    stage_tile<8>(Wfc_h, DD, 0, k0, Bs, w, l);
    __syncthreads();
    bf16x8 af[4], bg[8];
#pragma unroll
    for (int mi = 0; mi < 4; ++mi) af[mi] = read_frag(As, mi * 16 + fr, ks);
#pragma unroll
    for (int ni = 0; ni < 8; ++ni)
      bg[ni] = read_frag(Bs, wn + ni * 16 + fr, ks);
#pragma unroll
    for (int mi = 0; mi < 4; ++mi)
#pragma unroll
      for (int ni = 0; ni < 8; ++ni)
        acc[mi][ni] = __builtin_amdgcn_mfma_f32_16x16x32_bf16(
            af[mi], bg[ni], acc[mi][ni], 0, 0, 0);
    __syncthreads();
  }
  float p1[4][4], p2[4][4];
#pragma unroll
  for (int mi = 0; mi < 4; ++mi)
#pragma unroll
    for (int j = 0; j < 4; ++j) {
      p1[mi][j] = 0.0f;
      p2[mi][j] = 0.0f;
    }
#pragma unroll
  for (int mi = 0; mi < 4; ++mi) {
    const int r = mi * 16 + ks * 4;
#pragma unroll
    for (int ni = 0; ni < 8; ++ni) {
      const int col = wn + ni * 16 + fr;
#pragma unroll
      for (int j = 0; j < 4; ++j) {
        const float val = acc[mi][ni][j] + q[(long)(bm + r + j) * DD + col];
        acc[mi][ni][j] = val;
        p1[mi][j] += val;
        p2[mi][j] += val * val;
      }
    }
  }
#pragma unroll
  for (int off = 1; off < 16; off <<= 1) {
#pragma unroll
    for (int mi = 0; mi < 4; ++mi)
#pragma unroll
      for (int j = 0; j < 4; ++j) {
        p1[mi][j] += __shfl_xor(p1[mi][j], off);
        p2[mi][j] += __shfl_xor(p2[mi][j], off);
      }
  }
  if (fr == 0) {
#pragma unroll
    for (int mi = 0; mi < 4; ++mi)
#pragma unroll
      for (int j = 0; j < 4; ++j) {
        red[0][mi * 16 + ks * 4 + j][w] = p1[mi][j];
        red[1][mi * 16 + ks * 4 + j][w] = p2[mi][j];
      }
  }
  __syncthreads();
#pragma unroll
  for (int mi = 0; mi < 4; ++mi) {
#pragma unroll
    for (int j = 0; j < 4; ++j) {
      const int r = mi * 16 + ks * 4 + j;
      const float s1 =
          red[0][r][0] + red[0][r][1] + red[0][r][2] + red[0][r][3];
      const float s2 =
          red[1][r][0] + red[1][r][1] + red[1][r][2] + red[1][r][3];
      const float mu = s1 * (1.0f / DD);
      const float rs = rsqrtf(s2 * (1.0f / DD) - mu * mu + 1e-6f);
#pragma unroll
      for (int ni = 0; ni < 8; ++ni) {
        const int col = wn + ni * 16 + fr;
        outO[(long)(bm + r) * DD + col] =
            (acc[mi][ni][j] - mu) * rs * gamma[col] + beta[col];
      }
    }
  }
}

// ---------------------------------------------------------------------------
extern "C" void kernel_launch(void* const* d_in, const int* in_sizes, int n_in,
                              void* d_out, int out_size, void* d_ws,
                              size_t ws_size, hipStream_t stream) {
  const float* q = (const float*)d_in[0];
  const float* k = (const float*)d_in[1];
  const float* v = (const float*)d_in[2];
  const int* lens = (const int*)d_in[3];
  const float* dist = (const float*)d_in[4];
  const float* Wq = (const float*)d_in[5];
  const float* Wk = (const float*)d_in[6];
  const float* Wv = (const float*)d_in[7];
  const float* Wqt = (const float*)d_in[8];
  const float* Wkt = (const float*)d_in[9];
  const float* Wfc = (const float*)d_in[10];
  const float* gamma = (const float*)d_in[11];
  const float* beta = (const float*)d_in[12];

  char* W = (char*)d_ws;
  const size_t SB = 16777216;  // bytes of one bf16 [16384][512] buffer
  u16* q_hi = (u16*)(W + 0 * SB);    // reused later as qt_h
  u16* q_lo = (u16*)(W + 1 * SB);    // reused later as qt_l
  u16* k_hi = (u16*)(W + 2 * SB);    // reused later as kt_h
  u16* k_lo = (u16*)(W + 3 * SB);    // reused later as kt_l
  u16* v_hi = (u16*)(W + 4 * SB);    // reused later as vpT
  u16* dist_h = (u16*)(W + 5 * SB);  // 2SB; reused later as attnB
  u16* dist_l = (u16*)(W + 7 * SB);  // 2SB
  u16* qp_bf = (u16*)(W + 9 * SB);   // reused later as out0
  u16* kp_bf = (u16*)(W + 10 * SB);
  u16* vp_bf = (u16*)(W + 11 * SB);
  u16* qt0h = (u16*)(W + 12 * SB);
  u16* qt0l = (u16*)(W + 13 * SB);
  u16* kt0h = (u16*)(W + 14 * SB);
  u16* kt0l = (u16*)(W + 15 * SB);
  u16* qT_h = (u16*)(W + 16 * SB);
  u16* qT_l = (u16*)(W + 17 * SB);
  u16* kT_h = (u16*)(W + 18 * SB);
  u16* kT_l = (u16*)(W + 19 * SB);
  char* WB = W + 20 * SB;
  const size_t WS = 524288;
  u16* Wq_h = (u16*)(WB + 0 * WS);
  u16* Wk_h = (u16*)(WB + 1 * WS);
  u16* Wv_h = (u16*)(WB + 2 * WS);
  u16* Wfc_h = (u16*)(WB + 3 * WS);
  u16* Wqt_h = (u16*)(WB + 4 * WS);
  u16* Wqt_l = (u16*)(WB + 5 * WS);
  u16* Wkt_h = (u16*)(WB + 6 * WS);
  u16* Wkt_l = (u16*)(WB + 7 * WS);
  // aliases (lifetimes disjoint, stream-ordered)
  u16* qt_h = q_hi;
  u16* qt_l = q_lo;
  u16* kt_h = k_hi;
  u16* kt_l = k_lo;
  u16* vpT = v_hi;
  u16* attnB = dist_h;
  u16* out0 = qp_bf;

  float* outO = (float*)d_out;
  float* attnF = outO + NLD;

  dim3 blk(256);
  k_split3<<<dim3(1024, 1, 3), blk, 0, stream>>>(q, k, v, q_hi, q_lo, k_hi,
                                                 k_lo, v_hi);
  k_splitd<<<4096, blk, 0, stream>>>(dist, dist_h, dist_l);
  k_splitw<<<dim3(256, 1, 6), blk, 0, stream>>>(Wq, Wk, Wv, Wfc, Wqt, Wkt,
                                                Wq_h, Wk_h, Wv_h, Wfc_h,
                                                Wqt_h, Wqt_l, Wkt_h, Wkt_l);

  k_proj_p<<<dim3(4, 128, 3), blk, 0, stream>>>(q_hi, k_hi, v_hi, Wq_h, Wk_h,
                                                Wv_h, lens, qp_bf, kp_bf,
                                                vp_bf);
  k_proj_t<<<dim3(4, 128, 2), blk, 0, stream>>>(q_hi, q_lo, k_hi, k_lo, Wqt_h,
                                                Wqt_l, Wkt_h, Wkt_l, qt0h,
                                                qt0l, kt0h, kt0l);
  k_tr<<<dim3(8, 16, 80), blk, 0, stream>>>(qt0h, qt0l, kt0h, kt0l, vp_bf,
                                            lens, qT_h, qT_l, kT_h, kT_l,
                                            vpT);
  k_dist_g<<<dim3(4, 8, 32), blk, 0, stream>>>(dist_h, dist_l, qT_h, qT_l,
                                               kT_h, kT_l, lens, qt_h, qt_l,
                                               kt_h, kt_l);
  k_score<<<dim3(8, 8, 16), blk, 0, stream>>>(qp_bf, kp_bf, qt_h, qt_l, kt_h,
                                              kt_l, lens, attnF, attnB);
  k_pv<<<dim3(4, 8, 16), blk, 0, stream>>>(attnB, vpT, lens, out0);
  k_fcln<<<dim3(256), blk, 0, stream>>>(out0, Wfc_h, q, gamma, beta, outO);
}